// Round 1
// baseline (344.613 us; speedup 1.0000x reference)
//
#include <hip/hip_runtime.h>
#include <hip/hip_bf16.h>
#include <math.h>

// S=4096, D_IN=D_OUT=2048.
// out = causal_softmax((xWq^T)(xWk^T)^T / sqrt(D)) @ (xWv^T)
// (post-softmax mask + renorm == causal softmax; denominators cancel)

typedef __attribute__((ext_vector_type(8))) short bf16x8;   // 8 bf16 (4 VGPRs)
typedef __attribute__((ext_vector_type(4))) float f32x4;    // 4 fp32
typedef __attribute__((ext_vector_type(8))) unsigned short u16x8;

__device__ __forceinline__ unsigned short f2bf(float f) {
  unsigned int u = __float_as_uint(f);
  u += 0x7FFFu + ((u >> 16) & 1u);   // RNE
  return (unsigned short)(u >> 16);
}

__device__ __forceinline__ void gload16(const unsigned short* g, unsigned short* l) {
  __builtin_amdgcn_global_load_lds(
      (const __attribute__((address_space(1))) void*)g,
      (__attribute__((address_space(3))) void*)l,
      16, 0, 0);
}

// ---------------- f32 -> bf16 convert (vectorized, 8 elems/thread) ---------
__global__ void cvt_f32_bf16(const float* __restrict__ in,
                             unsigned short* __restrict__ out, int n) {
  int i = (blockIdx.x * 256 + threadIdx.x) * 8;
  if (i >= n) return;
  float4 a = *(const float4*)(in + i);
  float4 b = *(const float4*)(in + i + 4);
  u16x8 r;
  r[0] = f2bf(a.x); r[1] = f2bf(a.y); r[2] = f2bf(a.z); r[3] = f2bf(a.w);
  r[4] = f2bf(b.x); r[5] = f2bf(b.y); r[6] = f2bf(b.z); r[7] = f2bf(b.w);
  *(u16x8*)(out + i) = r;
}

// ---------------- NT GEMM: C[M,N] = A[M,K] * B[N,K]^T ----------------------
// 128x128 tile, BK=64, 256 threads = 4 waves (2x2), 64x64 per wave,
// mfma_f32_16x16x32_bf16, global_load_lds width-16 staging, 2-barrier loop.
// OUT_MODE: 0 = bf16 out, 1 = f32 out. scale applied at store.
// CAUSAL_SKIP: skip tiles with bn > bm (QK^T).
// CAUSAL_KLIM: K-loop limited to (bm+1)*128 (P@V with causal-zero P).
template <int OUT_MODE, bool CAUSAL_SKIP, bool CAUSAL_KLIM>
__global__ void gemm_nt(const unsigned short* __restrict__ A,
                        const unsigned short* __restrict__ B,
                        void* __restrict__ Cout,
                        int M, int N, int K, float scale) {
  const int bn = blockIdx.x, bm = blockIdx.y;
  if (CAUSAL_SKIP && bn > bm) return;

  const int tid  = threadIdx.x;
  const int lane = tid & 63;
  const int w    = tid >> 6;          // wave 0..3
  const int wm   = (w >> 1) * 64;     // wave row offset in tile
  const int wn   = (w & 1) * 64;      // wave col offset in tile

  __shared__ __align__(16) unsigned short As[128 * 64];
  __shared__ __align__(16) unsigned short Bs[128 * 64];

  f32x4 acc[4][4] = {};

  int ktiles = K >> 6;
  if (CAUSAL_KLIM) {
    int lim = (bm + 1) * 2;           // (bm+1)*128 / 64
    if (lim < ktiles) ktiles = lim;
  }

  const int lrow  = lane >> 3;        // 0..7 (row within 8-row stripe)
  const int lslot = lane & 7;         // 0..7 (16B slot within 128B row)

  for (int kt = 0; kt < ktiles; ++kt) {
    __syncthreads();                  // prev tile's ds_reads done
    const int kcol = kt * 64 + lslot * 8;
#pragma unroll
    for (int p = 0; p < 4; ++p) {
      const int row = p * 32 + w * 8; // wave-uniform LDS base row
      gload16(A + (size_t)(bm * 128 + row + lrow) * K + kcol, &As[row * 64]);
      gload16(B + (size_t)(bn * 128 + row + lrow) * K + kcol, &Bs[row * 64]);
    }
    __syncthreads();                  // vmcnt(0) drained by compiler

#pragma unroll
    for (int ks = 0; ks < 2; ++ks) {
      bf16x8 af[4], bfr[4];
#pragma unroll
      for (int m = 0; m < 4; ++m)
        af[m] = *(const bf16x8*)&As[(wm + m * 16 + (lane & 15)) * 64 + ks * 32 + (lane >> 4) * 8];
#pragma unroll
      for (int n = 0; n < 4; ++n)
        bfr[n] = *(const bf16x8*)&Bs[(wn + n * 16 + (lane & 15)) * 64 + ks * 32 + (lane >> 4) * 8];
#pragma unroll
      for (int m = 0; m < 4; ++m)
#pragma unroll
        for (int n = 0; n < 4; ++n)
          acc[m][n] = __builtin_amdgcn_mfma_f32_16x16x32_bf16(af[m], bfr[n], acc[m][n], 0, 0, 0);
    }
  }

  // epilogue: C/D layout col=lane&15, row=(lane>>4)*4+reg  [m89-verified]
  const int crow0 = bm * 128 + wm + (lane >> 4) * 4;
  const int ccol0 = bn * 128 + wn + (lane & 15);
#pragma unroll
  for (int m = 0; m < 4; ++m) {
#pragma unroll
    for (int n = 0; n < 4; ++n) {
#pragma unroll
      for (int j = 0; j < 4; ++j) {
        const size_t r = (size_t)(crow0 + m * 16 + j);
        const size_t c = (size_t)(ccol0 + n * 16);
        const float v = acc[m][n][j] * scale;
        if (OUT_MODE == 0) ((unsigned short*)Cout)[r * N + c] = f2bf(v);
        else               ((float*)Cout)[r * N + c] = v;
      }
    }
  }
}

// ---------------- causal row softmax: scores f32 -> P bf16 -----------------
// One block (256 threads) per row i. Valid j in [0, i]; zero-pad to the
// enclosing 128-tile boundary so the PV GEMM's clamped K-loop reads zeros.
__global__ void softmax_causal(const float* __restrict__ Sc,
                               unsigned short* __restrict__ P, int S) {
  const int i = blockIdx.x;
  const int tid = threadIdx.x;
  const int nvalid = i + 1;
  const int pad_end = ((i >> 7) + 1) << 7;
  const float* row = Sc + (size_t)i * S;

  float v[16];
  int cnt = 0;
  float m = -1e30f;
  for (int j = tid; j < nvalid; j += 256) {
    float x = row[j];
    v[cnt++] = x;
    m = fmaxf(m, x);
  }
#pragma unroll
  for (int d = 1; d < 64; d <<= 1) m = fmaxf(m, __shfl_xor(m, d));
  __shared__ float red_m[4], red_s[4];
  const int lane = tid & 63, wv = tid >> 6;
  if (lane == 0) red_m[wv] = m;
  __syncthreads();
  m = fmaxf(fmaxf(red_m[0], red_m[1]), fmaxf(red_m[2], red_m[3]));

  float s = 0.0f;
  cnt = 0;
  for (int j = tid; j < nvalid; j += 256) {
    float e = __expf(v[cnt] - m);
    v[cnt] = e;
    s += e;
    ++cnt;
  }
#pragma unroll
  for (int d = 1; d < 64; d <<= 1) s += __shfl_xor(s, d);
  if (lane == 0) red_s[wv] = s;
  __syncthreads();
  s = red_s[0] + red_s[1] + red_s[2] + red_s[3];

  const float inv = 1.0f / s;
  unsigned short* prow = P + (size_t)i * S;
  cnt = 0;
  for (int j = tid; j < pad_end; j += 256) {
    unsigned short o = 0;
    if (j < nvalid) o = f2bf(v[cnt++] * inv);
    prow[j] = o;
  }
}

// ---------------- launch ---------------------------------------------------
extern "C" void kernel_launch(void* const* d_in, const int* in_sizes, int n_in,
                              void* d_out, int out_size, void* d_ws, size_t ws_size,
                              hipStream_t stream) {
  const float* x  = (const float*)d_in[0];
  const float* Wq = (const float*)d_in[1];
  const float* Wk = (const float*)d_in[2];
  const float* Wv = (const float*)d_in[3];
  float* out = (float*)d_out;

  const int S = 4096, D = 2048;
  char* ws = (char*)d_ws;
  const size_t MB = 1u << 20;
  // Layout (144 MiB total). xb/w*b live inside the scores region (dead by
  // the time scores are written).
  float*          sc  = (float*)ws;                          // 64 MiB
  unsigned short* xb  = (unsigned short*)ws;                 // 16 MiB
  unsigned short* wqb = (unsigned short*)(ws + 16 * MB);     //  8 MiB
  unsigned short* wkb = (unsigned short*)(ws + 24 * MB);     //  8 MiB
  unsigned short* wvb = (unsigned short*)(ws + 32 * MB);     //  8 MiB
  unsigned short* Q   = (unsigned short*)(ws + 64 * MB);     // 16 MiB
  unsigned short* Kb  = (unsigned short*)(ws + 80 * MB);     // 16 MiB
  unsigned short* Vt  = (unsigned short*)(ws + 96 * MB);     // 16 MiB
  unsigned short* P   = (unsigned short*)(ws + 112 * MB);    // 32 MiB

  // 1) f32 -> bf16
  cvt_f32_bf16<<<(S * D) / (256 * 8), 256, 0, stream>>>(x, xb, S * D);
  cvt_f32_bf16<<<(D * D) / (256 * 8), 256, 0, stream>>>(Wq, wqb, D * D);
  cvt_f32_bf16<<<(D * D) / (256 * 8), 256, 0, stream>>>(Wk, wkb, D * D);
  cvt_f32_bf16<<<(D * D) / (256 * 8), 256, 0, stream>>>(Wv, wvb, D * D);

  // 2) projections: Q = x Wq^T, K = x Wk^T, Vt = (x Wv^T)^T = Wv x^T
  gemm_nt<0, false, false><<<dim3(D / 128, S / 128), 256, 0, stream>>>(xb, wqb, Q, S, D, D, 1.0f);
  gemm_nt<0, false, false><<<dim3(D / 128, S / 128), 256, 0, stream>>>(xb, wkb, Kb, S, D, D, 1.0f);
  gemm_nt<0, false, false><<<dim3(S / 128, D / 128), 256, 0, stream>>>(wvb, xb, Vt, D, S, D, 1.0f);

  // 3) scores = Q K^T * 1/sqrt(D), lower-triangular tiles only
  const float scale = 1.0f / sqrtf((float)D);
  gemm_nt<1, true, false><<<dim3(S / 128, S / 128), 256, 0, stream>>>(Q, Kb, sc, S, S, D, scale);

  // 4) causal softmax -> P (bf16, zero-padded to tile boundary)
  softmax_causal<<<S, 256, 0, stream>>>(sc, P, S);

  // 5) out = P Vt^T, K-loop clamped per row-block
  gemm_nt<1, false, true><<<dim3(D / 128, S / 128), 256, 0, stream>>>(P, Vt, out, S, D, S, 1.0f);
}

// Round 2
// 323.633 us; speedup vs baseline: 1.0648x; 1.0648x over previous
//
#include <hip/hip_runtime.h>
#include <hip/hip_bf16.h>
#include <math.h>

// S=4096, D=2048. out = causal_softmax((xWq^T)(xWk^T)^T / sqrt(D)) @ (xWv^T)
// 8-phase 256^2 GEMM template (T2 swizzle + T3/T4 counted vmcnt + T5 setprio).

typedef __attribute__((ext_vector_type(8))) short bf16x8;
typedef __attribute__((ext_vector_type(4))) float f32x4;
typedef __attribute__((ext_vector_type(8))) unsigned short u16x8;

__device__ __forceinline__ unsigned short f2bf(float f) {
  unsigned int u = __float_as_uint(f);
  u += 0x7FFFu + ((u >> 16) & 1u);   // RNE
  return (unsigned short)(u >> 16);
}

__device__ __forceinline__ void gload16(const unsigned short* g, unsigned short* l) {
  __builtin_amdgcn_global_load_lds(
      (const __attribute__((address_space(1))) void*)g,
      (__attribute__((address_space(3))) void*)l,
      16, 0, 0);
}

// ---------------- f32 -> bf16 convert ---------------------------------------
__global__ void cvt_f32_bf16(const float* __restrict__ in,
                             unsigned short* __restrict__ out, int n) {
  int i = (blockIdx.x * 256 + threadIdx.x) * 8;
  if (i >= n) return;
  float4 a = *(const float4*)(in + i);
  float4 b = *(const float4*)(in + i + 4);
  u16x8 r;
  r[0] = f2bf(a.x); r[1] = f2bf(a.y); r[2] = f2bf(a.z); r[3] = f2bf(a.w);
  r[4] = f2bf(b.x); r[5] = f2bf(b.y); r[6] = f2bf(b.z); r[7] = f2bf(b.w);
  *(u16x8*)(out + i) = r;
}

// ---------------- 8-phase 256x256 NT GEMM -----------------------------------
// C[M,N] = A[M,K] * B[N,K]^T. BM=BN=256, BK=64, 512 thr = 8 waves (2Mx4N),
// per-wave C = 128x64 (8x4 16x16 frags). LDS 128KB: [buf][mat][ks][256*32],
// K-half staging (256x32 = 16KB = 2 gload_lds/thread). Swizzle: 16B slot
// ^= (row>>1)&3 within 64B rows (pre-swizzled global source, linear LDS dest).
// Schedule per tile t (phases p0..p3 = (mh0,ks0),(mh1,ks0),(mh0,ks1),(mh1,ks1)):
//   p0 stages A-ks1(t+1), p1 B-ks1(t+1), p2 A-ks0(t+2), p3 B-ks0(t+2).
// Write-after-read: each staged region's old reads drained >=1 barrier earlier.
// Landing: vmcnt(8) at p1/p3 ends (tail: 8 -> 4 -> 0).
// CAUSAL: 0 none, 1 skip bn>bm (QK^T), 2 K-limit (bm+1)*4 tiles (PV).
#define STAGE(mat, ks, u)                                                     \
  do {                                                                        \
    if ((u) < ktiles) {                                                       \
      const unsigned short* _src = (mat) ? B : A;                             \
      const int _rb = (mat) ? brow_base : arow_base;                          \
      const int _hb = (((((u) & 1) << 1 | (mat)) << 1) | (ks)) << 13;         \
      _Pragma("unroll")                                                       \
      for (int _c = 0; _c < 2; ++_c) {                                        \
        const int _r0 = (w * 2 + _c) * 16;                                    \
        gload16(_src + (size_t)(_rb + _r0 + lrow) * K                         \
                     + ((u) * 64 + (ks) * 32 + gslot * 8),                    \
                &lds[_hb + _r0 * 32]);                                        \
      }                                                                       \
    }                                                                         \
  } while (0)

#define RD_A(buf, ks, gm)                                                     \
  (*(const bf16x8*)&lds[((((buf) << 2)) | (ks)) * 8192 +                      \
                        (wm * 128 + (gm) * 16 + rl) * 32 + rslot])
#define RD_B(buf, ks, n)                                                      \
  (*(const bf16x8*)&lds[((((buf) << 2)) | 2 | (ks)) * 8192 +                  \
                        (wn * 64 + (n) * 16 + rl) * 32 + rslot])

#define MFMA_BLOCK(mb)                                                        \
  _Pragma("unroll")                                                           \
  for (int _m = 0; _m < 4; ++_m)                                              \
    _Pragma("unroll")                                                         \
    for (int _n = 0; _n < 4; ++_n)                                            \
      acc[(mb) + _m][_n] = __builtin_amdgcn_mfma_f32_16x16x32_bf16(           \
          af[_m], bfv[_n], acc[(mb) + _m][_n], 0, 0, 0);

template <int OUT_MODE, int CAUSAL, bool FUSE>
__global__ __launch_bounds__(512, 2)
void gemm8(const unsigned short* __restrict__ A,
           const unsigned short* __restrict__ Bq,
           const unsigned short* __restrict__ Bk,
           void* __restrict__ Cq, void* __restrict__ Ck,
           int M, int N, int K, int nxHalf, float scale) {
  const int bn = blockIdx.x, bm = blockIdx.y;
  if (CAUSAL == 1 && bn > bm) return;

  const unsigned short* B = Bq;
  void* Cv = Cq;
  int bnl = bn;
  if (FUSE && bn >= nxHalf) { B = Bk; Cv = Ck; bnl = bn - nxHalf; }

  int ktiles = K >> 6;
  if (CAUSAL == 2) { const int lim = (bm + 1) << 2; if (lim < ktiles) ktiles = lim; }

  const int tid  = threadIdx.x;
  const int lane = tid & 63;
  const int w    = tid >> 6;         // wave 0..7
  const int wm   = w >> 2;           // 0..1
  const int wn   = w & 3;            // 0..3

  __shared__ __align__(16) unsigned short lds[65536];  // 128 KiB

  // staging lane geometry: 2 chunks/wave, chunk = 16 rows x 64B
  const int lrow  = lane >> 2;                       // 0..15
  const int gslot = (lane & 3) ^ ((lrow >> 1) & 3);  // pre-swizzled 16B slot
  const int arow_base = bm * 256;
  const int brow_base = bnl * 256;

  // fragment read geometry
  const int rl    = lane & 15;
  const int rslot = (((lane >> 4) ^ ((rl >> 1) & 3)) << 3);

  f32x4 acc[8][4] = {};

  // prologue: tile0 (A0,B0,A1,B1) + A-ks0(1), B-ks0(1); need first 2 landed
  STAGE(0, 0, 0); STAGE(1, 0, 0); STAGE(0, 1, 0); STAGE(1, 1, 0);
  STAGE(0, 0, 1); STAGE(1, 0, 1);
  asm volatile("s_waitcnt vmcnt(8)" ::: "memory");
  __builtin_amdgcn_s_barrier();

  for (int t = 0; t < ktiles; ++t) {
    const int buf = t & 1;
    bf16x8 af[4], bfv[4];
    // ---- phase 0: (mh0, ks0)
#pragma unroll
    for (int n = 0; n < 4; ++n) bfv[n] = RD_B(buf, 0, n);
#pragma unroll
    for (int m = 0; m < 4; ++m) af[m] = RD_A(buf, 0, m);
    STAGE(0, 1, t + 1);
    __builtin_amdgcn_s_barrier();
    __builtin_amdgcn_s_setprio(1);
    MFMA_BLOCK(0);
    __builtin_amdgcn_s_setprio(0);
    __builtin_amdgcn_s_barrier();
    // ---- phase 1: (mh1, ks0)
#pragma unroll
    for (int m = 0; m < 4; ++m) af[m] = RD_A(buf, 0, m + 4);
    STAGE(1, 1, t + 1);
    __builtin_amdgcn_s_barrier();
    __builtin_amdgcn_s_setprio(1);
    MFMA_BLOCK(4);
    __builtin_amdgcn_s_setprio(0);
    if (t < ktiles - 1) { asm volatile("s_waitcnt vmcnt(8)" ::: "memory"); }
    else                { asm volatile("s_waitcnt vmcnt(0)" ::: "memory"); }
    __builtin_amdgcn_s_barrier();
    // ---- phase 2: (mh0, ks1)
#pragma unroll
    for (int n = 0; n < 4; ++n) bfv[n] = RD_B(buf, 1, n);
#pragma unroll
    for (int m = 0; m < 4; ++m) af[m] = RD_A(buf, 1, m);
    STAGE(0, 0, t + 2);
    __builtin_amdgcn_s_barrier();
    __builtin_amdgcn_s_setprio(1);
    MFMA_BLOCK(0);
    __builtin_amdgcn_s_setprio(0);
    __builtin_amdgcn_s_barrier();
    // ---- phase 3: (mh1, ks1)
#pragma unroll
    for (int m = 0; m < 4; ++m) af[m] = RD_A(buf, 1, m + 4);
    STAGE(1, 0, t + 2);
    __builtin_amdgcn_s_barrier();
    __builtin_amdgcn_s_setprio(1);
    MFMA_BLOCK(4);
    __builtin_amdgcn_s_setprio(0);
    if (t < ktiles - 2)       { asm volatile("s_waitcnt vmcnt(8)" ::: "memory"); }
    else if (t == ktiles - 2) { asm volatile("s_waitcnt vmcnt(4)" ::: "memory"); }
    __builtin_amdgcn_s_barrier();
  }

  // epilogue: C/D layout col=lane&15, row=(lane>>4)*4+reg
  const int crow0 = bm * 256 + wm * 128 + ((lane >> 4) << 2);
  const int ccol0 = bnl * 256 + wn * 64 + (lane & 15);
#pragma unroll
  for (int m = 0; m < 8; ++m) {
#pragma unroll
    for (int n = 0; n < 4; ++n) {
#pragma unroll
      for (int j = 0; j < 4; ++j) {
        const size_t r = (size_t)(crow0 + m * 16 + j);
        const size_t c = (size_t)(ccol0 + n * 16);
        const float v = acc[m][n][j] * scale;
        if (OUT_MODE == 0) ((unsigned short*)Cv)[r * N + c] = f2bf(v);
        else               ((float*)Cv)[r * N + c] = v;
      }
    }
  }
}

// ---------------- causal row softmax: scores f32 -> P bf16 ------------------
// One block per row i; zero-pad P to the 256-tile boundary for PV's K-clamp.
__global__ void softmax_causal(const float* __restrict__ Sc,
                               unsigned short* __restrict__ P, int S) {
  const int i = blockIdx.x;
  const int tid = threadIdx.x;
  const int nvalid = i + 1;
  const int pad_end = ((i >> 8) + 1) << 8;
  const float* row = Sc + (size_t)i * S;

  float v[16];
  float m = -1e30f;
#pragma unroll
  for (int it = 0; it < 16; ++it) {
    const int j = tid + it * 256;
    const float x = (j < nvalid) ? row[j] : -1e30f;
    v[it] = x;
    m = fmaxf(m, x);
  }
#pragma unroll
  for (int d = 1; d < 64; d <<= 1) m = fmaxf(m, __shfl_xor(m, d));
  __shared__ float red_m[4], red_s[4];
  const int lane = tid & 63, wv = tid >> 6;
  if (lane == 0) red_m[wv] = m;
  __syncthreads();
  m = fmaxf(fmaxf(red_m[0], red_m[1]), fmaxf(red_m[2], red_m[3]));

  float s = 0.0f;
#pragma unroll
  for (int it = 0; it < 16; ++it) {
    const int j = tid + it * 256;
    const float e = (j < nvalid) ? __expf(v[it] - m) : 0.0f;
    v[it] = e;
    s += e;
  }
#pragma unroll
  for (int d = 1; d < 64; d <<= 1) s += __shfl_xor(s, d);
  if (lane == 0) red_s[wv] = s;
  __syncthreads();
  s = red_s[0] + red_s[1] + red_s[2] + red_s[3];

  const float inv = 1.0f / s;
  unsigned short* prow = P + (size_t)i * S;
#pragma unroll
  for (int it = 0; it < 16; ++it) {
    const int j = tid + it * 256;
    if (j < pad_end) prow[j] = (j < nvalid) ? f2bf(v[it] * inv) : (unsigned short)0;
  }
}

// ---------------- launch -----------------------------------------------------
extern "C" void kernel_launch(void* const* d_in, const int* in_sizes, int n_in,
                              void* d_out, int out_size, void* d_ws, size_t ws_size,
                              hipStream_t stream) {
  const float* x  = (const float*)d_in[0];
  const float* Wq = (const float*)d_in[1];
  const float* Wk = (const float*)d_in[2];
  const float* Wv = (const float*)d_in[3];
  float* out = (float*)d_out;

  const int S = 4096, D = 2048;
  char* ws = (char*)d_ws;
  const size_t MB = 1u << 20;
  float*          sc  = (float*)ws;                          // 64 MiB
  unsigned short* xb  = (unsigned short*)ws;                 // 16 MiB (dead before sc)
  unsigned short* wqb = (unsigned short*)(ws + 16 * MB);     //  8 MiB
  unsigned short* wkb = (unsigned short*)(ws + 24 * MB);     //  8 MiB
  unsigned short* wvb = (unsigned short*)(ws + 32 * MB);     //  8 MiB
  unsigned short* Q   = (unsigned short*)(ws + 64 * MB);     // 16 MiB
  unsigned short* Kb  = (unsigned short*)(ws + 80 * MB);     // 16 MiB
  unsigned short* Vt  = (unsigned short*)(ws + 96 * MB);     // 16 MiB
  unsigned short* P   = (unsigned short*)(ws + 112 * MB);    // 32 MiB

  // 1) f32 -> bf16
  cvt_f32_bf16<<<(S * D) / (256 * 8), 256, 0, stream>>>(x, xb, S * D);
  cvt_f32_bf16<<<(D * D) / (256 * 8), 256, 0, stream>>>(Wq, wqb, D * D);
  cvt_f32_bf16<<<(D * D) / (256 * 8), 256, 0, stream>>>(Wk, wkb, D * D);
  cvt_f32_bf16<<<(D * D) / (256 * 8), 256, 0, stream>>>(Wv, wvb, D * D);

  // 2) fused Q/K projections (256 blocks), then Vt = Wv x^T (128 blocks)
  gemm8<0, 0, true><<<dim3(16, 16), 512, 0, stream>>>(xb, wqb, wkb, Q, Kb,
                                                      S, D, D, 8, 1.0f);
  gemm8<0, 0, false><<<dim3(16, 8), 512, 0, stream>>>(wvb, xb, nullptr, Vt, nullptr,
                                                      D, S, D, 0, 1.0f);

  // 3) scores = Q K^T / sqrt(D), lower-triangular 256-tiles only
  const float scale = 1.0f / sqrtf((float)D);
  gemm8<1, 1, false><<<dim3(16, 16), 512, 0, stream>>>(Q, Kb, nullptr, sc, nullptr,
                                                       S, S, D, 0, scale);

  // 4) causal softmax -> P (bf16, zero-padded to 256 boundary)
  softmax_causal<<<S, 256, 0, stream>>>(sc, P, S);

  // 5) out = P Vt^T, K-loop clamped per 256-row block
  gemm8<1, 2, false><<<dim3(8, 16), 512, 0, stream>>>(P, Vt, nullptr, out, nullptr,
                                                      S, D, S, 0, 1.0f);
}

// Round 4
// 314.699 us; speedup vs baseline: 1.0951x; 1.0284x over previous
//
#include <hip/hip_runtime.h>
#include <hip/hip_bf16.h>
#include <math.h>

// S=4096, D=2048. out = causal_softmax((xWq^T)(xWk^T)^T / sqrt(D)) @ (xWv^T)
// 256^2 8-phase GEMM core: asm ds_read_b128 (no compiler drains), 128B-segment
// global_load_lds staging, XOR row-swizzle, counted waits, setprio.
// R4 fix: workspace repack — xb no longer aliases sc (R3's vt_qkt merged the
// Vt GEMM (reads xb) with QK^T (writes sc) into one dispatch -> race -> NaN).

typedef __attribute__((ext_vector_type(8))) short bf16x8;
typedef __attribute__((ext_vector_type(4))) float f32x4;
typedef __attribute__((ext_vector_type(8))) unsigned short u16x8;
typedef __attribute__((ext_vector_type(4))) int iv4;

__device__ __forceinline__ unsigned short f2bf(float f) {
  unsigned int u = __float_as_uint(f);
  u += 0x7FFFu + ((u >> 16) & 1u);   // RNE
  return (unsigned short)(u >> 16);
}

__device__ __forceinline__ void gload16(const unsigned short* g, unsigned short* l) {
  __builtin_amdgcn_global_load_lds(
      (const __attribute__((address_space(1))) void*)g,
      (__attribute__((address_space(3))) void*)l,
      16, 0, 0);
}

template <int OFF>
__device__ __forceinline__ bf16x8 dsr(unsigned addr) {
  iv4 r;
  asm volatile("ds_read_b128 %0, %1 offset:%2" : "=v"(r) : "v"(addr), "i"(OFF));
  return __builtin_bit_cast(bf16x8, r);
}

// ---------------- f32 -> bf16 convert ---------------------------------------
__global__ void cvt_f32_bf16(const float* __restrict__ in,
                             unsigned short* __restrict__ out, int n) {
  int i = (blockIdx.x * 256 + threadIdx.x) * 8;
  if (i >= n) return;
  float4 a = *(const float4*)(in + i);
  float4 b = *(const float4*)(in + i + 4);
  u16x8 r;
  r[0] = f2bf(a.x); r[1] = f2bf(a.y); r[2] = f2bf(a.z); r[3] = f2bf(a.w);
  r[4] = f2bf(b.x); r[5] = f2bf(b.y); r[6] = f2bf(b.z); r[7] = f2bf(b.w);
  *(u16x8*)(out + i) = r;
}

// ---------------- 256x256 GEMM core ------------------------------------------
// C[256,256] = A_blk[256,K] * B_blk[256,K]^T (NT). BK=64, 512 thr = 8 waves
// (2Mx4N), per-wave C 128x64 (8x4 frags of 16x16).
// LDS 128KB: region(buf,mat,half) = 128 rows x 64 cols (16KB), content
// LDS[row][t] = G[row][t ^ (row&7)] (16B slots). Staging: 2 gload_lds/region/
// thread, 128B contiguous per 8 lanes, pre-swizzled global source.
// Per tile t: 4 phases (mh0/ks0, mh1/ks0, mh0/ks1, mh1/ks1); stage tile t+1's
// A-halves at p0, B-halves at p1 (other buffer; WAR-safe — prior reads of that
// buffer drained >=1 barrier earlier). One vmcnt(0)+barrier per tile at p3 end
// (loads get ~3 phases of flight; barrier publishes cross-wave).
#define STG(P0, P1, matv, halfv, bufv)                                        \
  do {                                                                        \
    unsigned short* _d =                                                      \
        lds + ((((bufv) * 2 + (matv)) * 2 + (halfv)) * 8192) + (w * 8) * 64;  \
    gload16((P0), _d);                                                        \
    gload16((P1), _d + 4096);                                                 \
  } while (0)

#define LGKM_SB()                                         \
  asm volatile("s_waitcnt lgkmcnt(0)" ::: "memory");      \
  __builtin_amdgcn_sched_barrier(0)

#define MFMA_BLOCK(mb)                                                        \
  _Pragma("unroll")                                                           \
  for (int _m = 0; _m < 4; ++_m)                                              \
    _Pragma("unroll")                                                         \
    for (int _n = 0; _n < 4; ++_n)                                            \
      acc[(mb) + _m][_n] = __builtin_amdgcn_mfma_f32_16x16x32_bf16(           \
          af[_m], bfv[_n], acc[(mb) + _m][_n], 0, 0, 0);

__device__ __forceinline__ void gemm_core(const unsigned short* __restrict__ Ab,
                                          const unsigned short* __restrict__ Bb,
                                          unsigned short* lds, int K, int ktiles,
                                          f32x4 (&acc)[8][4]) {
  const int tid  = threadIdx.x;
  const int lane = tid & 63;
  const int w    = tid >> 6;          // 0..7
  const int wm   = w >> 2;            // 0..1
  const int wn   = w & 3;             // 0..3

  // ---- staging geometry: lane l -> row (l>>3), slot (l&7); fetch global
  // slot (l&7)^((l>>3)&7) so LDS[row][t] = G[row][t^(row&7)].
  const int srow  = w * 8 + (lane >> 3);
  const int gslot = (lane & 7) ^ ((lane >> 3) & 7);
  const unsigned short* pA00 = Ab + (size_t)(srow +   0) * K + gslot * 8;
  const unsigned short* pA01 = Ab + (size_t)(srow +  64) * K + gslot * 8;
  const unsigned short* pA10 = Ab + (size_t)(srow + 128) * K + gslot * 8;
  const unsigned short* pA11 = Ab + (size_t)(srow + 192) * K + gslot * 8;
  const unsigned short* pB00 = Bb + (size_t)(srow +   0) * K + gslot * 8;
  const unsigned short* pB01 = Bb + (size_t)(srow +  64) * K + gslot * 8;
  const unsigned short* pB10 = Bb + (size_t)(srow + 128) * K + gslot * 8;
  const unsigned short* pB11 = Bb + (size_t)(srow + 192) * K + gslot * 8;

  // ---- read geometry (byte addrs for asm ds_read_b128)
  const unsigned lb = (unsigned)(size_t)&lds[0];
  const int rl = lane & 15, g = lane >> 4;
  const unsigned sw0 = (unsigned)(((0 + g) ^ (rl & 7)) * 16);   // ks0 slot swz
  const unsigned sw1 = (unsigned)(((4 + g) ^ (rl & 7)) * 16);   // ks1 slot swz
  // A region(buf, half=wm): byte base = buf*65536 + wm*16384; row rl*128.
  const unsigned rA = lb + (unsigned)(wm * 16384 + rl * 128);
  // B region(buf, half=wn>>1) + (wn&1)*64 rows.
  const unsigned rB = lb + (unsigned)(32768 + (wn >> 1) * 16384 +
                                      (wn & 1) * 8192 + rl * 128);

#pragma unroll
  for (int m = 0; m < 8; ++m)
#pragma unroll
    for (int n = 0; n < 4; ++n) acc[m][n] = f32x4{0.f, 0.f, 0.f, 0.f};

  // ---- prologue: stage tile0 into buf0, drain, publish
  STG(pA00, pA01, 0, 0, 0); STG(pA10, pA11, 0, 1, 0);
  STG(pB00, pB01, 1, 0, 0); STG(pB10, pB11, 1, 1, 0);
  pA00 += 64; pA01 += 64; pA10 += 64; pA11 += 64;
  pB00 += 64; pB01 += 64; pB10 += 64; pB11 += 64;
  asm volatile("s_waitcnt vmcnt(0)" ::: "memory");
  __builtin_amdgcn_s_barrier();

  for (int t = 0; t < ktiles; ++t) {
    const unsigned bo = (unsigned)(t & 1) << 16;
    const int nb = (t + 1) & 1;
    const bool st = (t + 1) < ktiles;
    const unsigned aA0 = rA + bo + sw0, aB0 = rB + bo + sw0;
    const unsigned aA1 = rA + bo + sw1, aB1 = rB + bo + sw1;
    bf16x8 af[4], bfv[4];
    // ---- p0: (mh0, ks0) ; stage A(t+1)
    bfv[0] = dsr<0>(aB0); bfv[1] = dsr<2048>(aB0);
    bfv[2] = dsr<4096>(aB0); bfv[3] = dsr<6144>(aB0);
    af[0] = dsr<0>(aA0); af[1] = dsr<2048>(aA0);
    af[2] = dsr<4096>(aA0); af[3] = dsr<6144>(aA0);
    if (st) { STG(pA00, pA01, 0, 0, nb); STG(pA10, pA11, 0, 1, nb); }
    __builtin_amdgcn_s_barrier();
    LGKM_SB();
    __builtin_amdgcn_s_setprio(1);
    MFMA_BLOCK(0);
    __builtin_amdgcn_s_setprio(0);
    __builtin_amdgcn_s_barrier();
    // ---- p1: (mh1, ks0) ; stage B(t+1)
    af[0] = dsr<8192>(aA0); af[1] = dsr<10240>(aA0);
    af[2] = dsr<12288>(aA0); af[3] = dsr<14336>(aA0);
    if (st) { STG(pB00, pB01, 1, 0, nb); STG(pB10, pB11, 1, 1, nb); }
    __builtin_amdgcn_s_barrier();
    LGKM_SB();
    __builtin_amdgcn_s_setprio(1);
    MFMA_BLOCK(4);
    __builtin_amdgcn_s_setprio(0);
    __builtin_amdgcn_s_barrier();
    // ---- p2: (mh0, ks1)
    bfv[0] = dsr<0>(aB1); bfv[1] = dsr<2048>(aB1);
    bfv[2] = dsr<4096>(aB1); bfv[3] = dsr<6144>(aB1);
    af[0] = dsr<0>(aA1); af[1] = dsr<2048>(aA1);
    af[2] = dsr<4096>(aA1); af[3] = dsr<6144>(aA1);
    __builtin_amdgcn_s_barrier();
    LGKM_SB();
    __builtin_amdgcn_s_setprio(1);
    MFMA_BLOCK(0);
    __builtin_amdgcn_s_setprio(0);
    __builtin_amdgcn_s_barrier();
    // ---- p3: (mh1, ks1) ; tile-boundary drain + publish
    af[0] = dsr<8192>(aA1); af[1] = dsr<10240>(aA1);
    af[2] = dsr<12288>(aA1); af[3] = dsr<14336>(aA1);
    __builtin_amdgcn_s_barrier();
    LGKM_SB();
    __builtin_amdgcn_s_setprio(1);
    MFMA_BLOCK(4);
    __builtin_amdgcn_s_setprio(0);
    asm volatile("s_waitcnt vmcnt(0)" ::: "memory");
    __builtin_amdgcn_s_barrier();
    pA00 += 64; pA01 += 64; pA10 += 64; pA11 += 64;
    pB00 += 64; pB01 += 64; pB10 += 64; pB11 += 64;
  }
}

// epilogue: C/D layout col=lane&15, row=(lane>>4)*4+reg
__device__ __forceinline__ void ep_f32(float* C, const f32x4 (&acc)[8][4],
                                       int r0, int c0, int ldc, float scale) {
  const int lane = threadIdx.x & 63, w = threadIdx.x >> 6;
  const int crow0 = r0 + (w >> 2) * 128 + ((lane >> 4) << 2);
  const int ccol0 = c0 + (w & 3) * 64 + (lane & 15);
#pragma unroll
  for (int m = 0; m < 8; ++m)
#pragma unroll
    for (int n = 0; n < 4; ++n)
#pragma unroll
      for (int j = 0; j < 4; ++j)
        C[(size_t)(crow0 + m * 16 + j) * ldc + (ccol0 + n * 16)] =
            acc[m][n][j] * scale;
}

__device__ __forceinline__ void ep_bf16(unsigned short* C, const f32x4 (&acc)[8][4],
                                        int r0, int c0, int ldc) {
  const int lane = threadIdx.x & 63, w = threadIdx.x >> 6;
  const int crow0 = r0 + (w >> 2) * 128 + ((lane >> 4) << 2);
  const int ccol0 = c0 + (w & 3) * 64 + (lane & 15);
#pragma unroll
  for (int m = 0; m < 8; ++m)
#pragma unroll
    for (int n = 0; n < 4; ++n)
#pragma unroll
      for (int j = 0; j < 4; ++j)
        C[(size_t)(crow0 + m * 16 + j) * ldc + (ccol0 + n * 16)] =
            f2bf(acc[m][n][j]);
}

// ---------------- kernels ----------------------------------------------------
// Fused Q/K projection: 256 blocks, XCD-swizzled (nwg%8==0).
__global__ __launch_bounds__(512, 2)
void proj_qk(const unsigned short* __restrict__ xb,
             const unsigned short* __restrict__ wqb,
             const unsigned short* __restrict__ wkb,
             unsigned short* __restrict__ Q, unsigned short* __restrict__ Kb) {
  __shared__ __align__(16) unsigned short lds[65536];
  const int bid = blockIdx.x;
  const int wg = (bid & 7) * 32 + (bid >> 3);   // XCD-contiguous chunks
  const int bm = wg >> 4, bnr = wg & 15;
  const unsigned short* B = (bnr < 8) ? wqb : wkb;
  unsigned short* C = (bnr < 8) ? Q : Kb;
  const int bnl = bnr & 7;
  f32x4 acc[8][4];
  gemm_core(xb + (size_t)bm * 256 * 2048, B + (size_t)bnl * 256 * 2048,
            lds, 2048, 32, acc);
  ep_bf16(C, acc, bm * 256, bnl * 256, 2048);
}

// Merged: QK^T (136 lower-tri tiles, f32+scale) + Vt = Wv x^T (128 tiles, bf16).
__global__ __launch_bounds__(512, 2)
void vt_qkt(const unsigned short* __restrict__ Qp,
            const unsigned short* __restrict__ Kp,
            const unsigned short* __restrict__ wvb,
            const unsigned short* __restrict__ xb,
            float* __restrict__ sc, unsigned short* __restrict__ Vt,
            float scale) {
  __shared__ __align__(16) unsigned short lds[65536];
  const int id = blockIdx.x;
  const unsigned short *Ab, *Bb;
  int r0, c0;
  bool isq;
  if (id < 136) {
    int bm = 0;
    while ((bm + 1) * (bm + 2) / 2 <= id) ++bm;
    const int bn = id - bm * (bm + 1) / 2;
    Ab = Qp + (size_t)bm * 256 * 2048; Bb = Kp + (size_t)bn * 256 * 2048;
    r0 = bm * 256; c0 = bn * 256; isq = true;
  } else {
    const int v = id - 136, bm = v >> 4, bn = v & 15;
    Ab = wvb + (size_t)bm * 256 * 2048; Bb = xb + (size_t)bn * 256 * 2048;
    r0 = bm * 256; c0 = bn * 256; isq = false;
  }
  f32x4 acc[8][4];
  gemm_core(Ab, Bb, lds, 2048, 32, acc);
  if (isq) ep_f32(sc, acc, r0, c0, 4096, scale);
  else     ep_bf16(Vt, acc, r0, c0, 4096);
}

// PV: out = P Vt^T, K clamped to (bm+1)*256.
__global__ __launch_bounds__(512, 2)
void pv(const unsigned short* __restrict__ P,
        const unsigned short* __restrict__ Vt, float* __restrict__ out) {
  __shared__ __align__(16) unsigned short lds[65536];
  const int bn = blockIdx.x, bm = blockIdx.y;
  int kt = (bm + 1) * 4;
  if (kt > 64) kt = 64;
  f32x4 acc[8][4];
  gemm_core(P + (size_t)bm * 256 * 4096, Vt + (size_t)bn * 256 * 4096,
            lds, 4096, kt, acc);
  ep_f32(out, acc, bm * 256, bn * 256, 2048, 1.0f);
}

// ---------------- causal row softmax: scores f32 -> P bf16 ------------------
__global__ void softmax_causal(const float* __restrict__ Sc,
                               unsigned short* __restrict__ P, int S) {
  const int i = blockIdx.x;
  const int tid = threadIdx.x;
  const int nvalid = i + 1;
  const int pad_end = ((i >> 8) + 1) << 8;   // 256-tile boundary
  const float* row = Sc + (size_t)i * S;

  float v[16];
  float m = -1e30f;
#pragma unroll
  for (int it = 0; it < 16; ++it) {
    const int j = tid + it * 256;
    const float x = (j < nvalid) ? row[j] : -1e30f;
    v[it] = x;
    m = fmaxf(m, x);
  }
#pragma unroll
  for (int d = 1; d < 64; d <<= 1) m = fmaxf(m, __shfl_xor(m, d));
  __shared__ float red_m[4], red_s[4];
  const int lane = tid & 63, wv = tid >> 6;
  if (lane == 0) red_m[wv] = m;
  __syncthreads();
  m = fmaxf(fmaxf(red_m[0], red_m[1]), fmaxf(red_m[2], red_m[3]));

  float s = 0.0f;
#pragma unroll
  for (int it = 0; it < 16; ++it) {
    const int j = tid + it * 256;
    const float e = (j < nvalid) ? __expf(v[it] - m) : 0.0f;
    v[it] = e;
    s += e;
  }
#pragma unroll
  for (int d = 1; d < 64; d <<= 1) s += __shfl_xor(s, d);
  if (lane == 0) red_s[wv] = s;
  __syncthreads();
  s = red_s[0] + red_s[1] + red_s[2] + red_s[3];

  const float inv = 1.0f / s;
  unsigned short* prow = P + (size_t)i * S;
#pragma unroll
  for (int it = 0; it < 16; ++it) {
    const int j = tid + it * 256;
    if (j < pad_end) prow[j] = (j < nvalid) ? f2bf(v[it] * inv) : (unsigned short)0;
  }
}

// ---------------- launch -----------------------------------------------------
extern "C" void kernel_launch(void* const* d_in, const int* in_sizes, int n_in,
                              void* d_out, int out_size, void* d_ws, size_t ws_size,
                              hipStream_t stream) {
  const float* x  = (const float*)d_in[0];
  const float* Wq = (const float*)d_in[1];
  const float* Wk = (const float*)d_in[2];
  const float* Wv = (const float*)d_in[3];
  float* out = (float*)d_out;

  const int S = 4096, D = 2048;
  char* ws = (char*)d_ws;
  const size_t MB = 1u << 20;
  // Workspace (max 136 MiB; 144 MiB proven available in R1):
  //   sc  [  0, 64)  f32 scores           live: vt_qkt .. softmax
  //   xb  [ 64, 80)  bf16 x               live: cvt .. vt_qkt
  //   wqb [ 80, 88)  wkb [88,96)          live: cvt .. proj_qk
  //   wvb [ 96,104)                       live: cvt .. vt_qkt
  //   Q   [104,120)  Kb  [120,136)        live: proj_qk .. vt_qkt
  //   Vt  [ 80, 96)  (over wqb/wkb, dead) live: vt_qkt .. pv
  //   P   [104,136)  (over Q/Kb, dead)    live: softmax .. pv
  float*          sc  = (float*)ws;
  unsigned short* xb  = (unsigned short*)(ws + 64 * MB);
  unsigned short* wqb = (unsigned short*)(ws + 80 * MB);
  unsigned short* wkb = (unsigned short*)(ws + 88 * MB);
  unsigned short* wvb = (unsigned short*)(ws + 96 * MB);
  unsigned short* Q   = (unsigned short*)(ws + 104 * MB);
  unsigned short* Kb  = (unsigned short*)(ws + 120 * MB);
  unsigned short* Vt  = (unsigned short*)(ws + 80 * MB);
  unsigned short* P   = (unsigned short*)(ws + 104 * MB);

  cvt_f32_bf16<<<(S * D) / (256 * 8), 256, 0, stream>>>(x, xb, S * D);
  cvt_f32_bf16<<<(D * D) / (256 * 8), 256, 0, stream>>>(Wq, wqb, D * D);
  cvt_f32_bf16<<<(D * D) / (256 * 8), 256, 0, stream>>>(Wk, wkb, D * D);
  cvt_f32_bf16<<<(D * D) / (256 * 8), 256, 0, stream>>>(Wv, wvb, D * D);

  proj_qk<<<256, 512, 0, stream>>>(xb, wqb, wkb, Q, Kb);

  const float scale = 1.0f / sqrtf((float)D);
  vt_qkt<<<264, 512, 0, stream>>>(Q, Kb, wvb, xb, sc, Vt, scale);

  softmax_causal<<<S, 256, 0, stream>>>(sc, P, S);

  pv<<<dim3(8, 16), 512, 0, stream>>>(P, Vt, out);
}

// Round 5
// 306.212 us; speedup vs baseline: 1.1254x; 1.0277x over previous
//
#include <hip/hip_runtime.h>
#include <hip/hip_bf16.h>
#include <math.h>

// S=4096, D=2048. out = causal_softmax((xWq^T)(xWk^T)^T / sqrt(D)) @ (xWv^T)
// R5: m201-style counted-vmcnt pipeline. Quadrant phases with read-once frag
// reuse; stage units (A-mh / B-nh, 16KB each) rotate 3-in-flight; vmcnt(6)
// once per tile (never drain to 0 mid-loop).

typedef __attribute__((ext_vector_type(8))) short bf16x8;
typedef __attribute__((ext_vector_type(4))) float f32x4;
typedef __attribute__((ext_vector_type(8))) unsigned short u16x8;
typedef __attribute__((ext_vector_type(4))) int iv4;

__device__ __forceinline__ unsigned short f2bf(float f) {
  unsigned int u = __float_as_uint(f);
  u += 0x7FFFu + ((u >> 16) & 1u);   // RNE
  return (unsigned short)(u >> 16);
}

__device__ __forceinline__ void gload16(const unsigned short* g, unsigned short* l) {
  __builtin_amdgcn_global_load_lds(
      (const __attribute__((address_space(1))) void*)g,
      (__attribute__((address_space(3))) void*)l,
      16, 0, 0);
}

template <int OFF>
__device__ __forceinline__ bf16x8 dsr(unsigned addr) {
  iv4 r;
  asm volatile("ds_read_b128 %0, %1 offset:%2" : "=v"(r) : "v"(addr), "i"(OFF));
  return __builtin_bit_cast(bf16x8, r);
}

// ---------------- f32 -> bf16 convert ---------------------------------------
__global__ void cvt_f32_bf16(const float* __restrict__ in,
                             unsigned short* __restrict__ out, int n) {
  int i = (blockIdx.x * 256 + threadIdx.x) * 8;
  if (i >= n) return;
  float4 a = *(const float4*)(in + i);
  float4 b = *(const float4*)(in + i + 4);
  u16x8 r;
  r[0] = f2bf(a.x); r[1] = f2bf(a.y); r[2] = f2bf(a.z); r[3] = f2bf(a.w);
  r[4] = f2bf(b.x); r[5] = f2bf(b.y); r[6] = f2bf(b.z); r[7] = f2bf(b.w);
  *(u16x8*)(out + i) = r;
}

// ---------------- 256x256 GEMM core (counted-vmcnt pipeline) -----------------
// C[256,256] = A_blk[256,K] * B_blk[256,K]^T. BK=64, 512 thr = 8 waves (2Mx4N),
// per-wave C 128x64. LDS 128KB = 2 bufs x {A:2 units, B:2 units} x 16KB.
// Unit row permutation (LDS row -> global row):
//   A unit mh, row p (128 rows): grow = (p>>6)*128 + mh*64 + (p&63)
//   B unit nh, row p:            grow = (p>>5)*64  + nh*32 + (p&31)
// Column swizzle: LDS[p][s16] = G[grow][s16 ^ (p&7)], via pre-swizzled source.
// Phases (tile t) = C-quadrants, frags read ONCE and register-reused:
//   p0 (mh0,nh0): read A-h0(12B? 8) + B-n0(4); stage B-n1(t+1)
//   p1 (mh1,nh0): read A-h1(8);               stage A-h0(t+2)
//   p2 (mh0,nh1): read B-n1(4);               stage B-n0(t+2)
//   p3 (mh1,nh1): no reads;                   stage A-h1(t+2)
//   p3 end: vmcnt(6) (t<=kt-3) / vmcnt(0) (t==kt-2) / none (t==kt-1); barrier.
// WAR-safe: each staged unit's last reads were issued >=1 barrier earlier.
// Landing: vmcnt(6) leaves exactly the 3 newest units in flight; everything
// tile t+1 needs has landed before p0(t+1).
#define LGKM_SB()                                         \
  asm volatile("s_waitcnt lgkmcnt(0)" ::: "memory");      \
  __builtin_amdgcn_sched_barrier(0)

#define QMFMA(MB, NB, AF, BV)                                                 \
  _Pragma("unroll")                                                           \
  for (int _fm = 0; _fm < 4; ++_fm)                                           \
    _Pragma("unroll")                                                         \
    for (int _fn = 0; _fn < 2; ++_fn)                                         \
      _Pragma("unroll")                                                       \
      for (int _ks = 0; _ks < 2; ++_ks)                                       \
        acc[(MB) + _fm][(NB) + _fn] = __builtin_amdgcn_mfma_f32_16x16x32_bf16( \
            AF[_fm * 2 + _ks], BV[_fn * 2 + _ks], acc[(MB) + _fm][(NB) + _fn], \
            0, 0, 0);

#define STG_A(mhv, tau, bufv)                                                 \
  do {                                                                        \
    unsigned short* _d = lds + (bufv) * 32768 + (mhv) * 8192 + w * 512;       \
    gload16(pA + (size_t)((mhv) * 64) * KC + ((size_t)(tau) << 6), _d);       \
    gload16(pA + (size_t)(128 + (mhv) * 64) * KC + ((size_t)(tau) << 6),      \
            _d + 4096);                                                       \
  } while (0)

#define STG_B(nhv, tau, bufv)                                                 \
  do {                                                                        \
    unsigned short* _d = lds + (bufv) * 32768 + 16384 + (nhv) * 8192 + w * 512;\
    gload16(pB + (size_t)((nhv) * 32) * KC + ((size_t)(tau) << 6), _d);       \
    gload16(pB + (size_t)(128 + (nhv) * 32) * KC + ((size_t)(tau) << 6),      \
            _d + 4096);                                                       \
  } while (0)

template <int KC>
__device__ __forceinline__ void gemm_core(const unsigned short* __restrict__ Ab,
                                          const unsigned short* __restrict__ Bb,
                                          unsigned short* lds, int ktiles,
                                          f32x4 (&acc)[8][4]) {
  const int tid  = threadIdx.x;
  const int lane = tid & 63;
  const int w    = tid >> 6;          // 0..7
  const int wm   = w >> 2;            // 0..1
  const int wn   = w & 3;             // 0..3

  // staging geometry: per gload, 64 lanes cover 8 rows x 128B; lane row
  // base = w*8 + (lane>>3); fetch global 16B-slot (lane&7)^((lane>>3)&7)
  // so LDS[p][s] = G[grow(p)][s ^ (p&7)].
  const int base  = w * 8 + (lane >> 3);           // 0..63
  const int gslot = (lane & 7) ^ ((lane >> 3) & 7);
  const unsigned short* pA = Ab + (size_t)base * KC + gslot * 8;
  const unsigned short* pB =
      Bb + (size_t)((base >> 5) * 64 + (base & 31)) * KC + gslot * 8;

  // read geometry (byte addrs for asm ds_read_b128)
  const unsigned lb = (unsigned)(size_t)&lds[0];
  const int rl = lane & 15, g = lane >> 4;
  const unsigned sw0 = (unsigned)(((0 + g) ^ (rl & 7)) * 16);
  const unsigned sw1 = (unsigned)(((4 + g) ^ (rl & 7)) * 16);
  const unsigned rA = lb + (unsigned)(wm * 8192 + rl * 128);
  const unsigned rB = lb + (unsigned)(wn * 4096 + rl * 128);

#pragma unroll
  for (int m = 0; m < 8; ++m)
#pragma unroll
    for (int n = 0; n < 4; ++n) acc[m][n] = f32x4{0.f, 0.f, 0.f, 0.f};

  // prologue: all of t0, then t1's first 3 units (B-n1(1) staged at p0(0))
  STG_A(0, 0, 0); STG_B(0, 0, 0); STG_A(1, 0, 0); STG_B(1, 0, 0);
  STG_A(0, 1, 1); STG_B(0, 1, 1); STG_A(1, 1, 1);
  asm volatile("s_waitcnt vmcnt(6)" ::: "memory");   // t0's 4 units landed
  __builtin_amdgcn_s_barrier();

  for (int t = 0; t < ktiles; ++t) {
    const unsigned bo = (unsigned)(t & 1) << 16;
    const int buf = t & 1, nb = (t + 1) & 1;
    const unsigned aA0 = rA + bo + sw0, aA1 = rA + bo + sw1;
    const unsigned aB0 = rB + bo + sw0, aB1 = rB + bo + sw1;
    bf16x8 af0[8], af1[8], bv0[4], bv1[4];
    // ---- p0 (mh0,nh0): read A-h0 + B-n0; stage B-n1(t+1)
    af0[0] = dsr<0>(aA0);     af0[1] = dsr<0>(aA1);
    af0[2] = dsr<2048>(aA0);  af0[3] = dsr<2048>(aA1);
    af0[4] = dsr<4096>(aA0);  af0[5] = dsr<4096>(aA1);
    af0[6] = dsr<6144>(aA0);  af0[7] = dsr<6144>(aA1);
    bv0[0] = dsr<32768>(aB0); bv0[1] = dsr<32768>(aB1);
    bv0[2] = dsr<34816>(aB0); bv0[3] = dsr<34816>(aB1);
    if (t + 1 < ktiles) STG_B(1, t + 1, nb);
    __builtin_amdgcn_s_barrier();
    LGKM_SB();
    __builtin_amdgcn_s_setprio(1);
    QMFMA(0, 0, af0, bv0);
    __builtin_amdgcn_s_setprio(0);
    __builtin_amdgcn_s_barrier();
    // ---- p1 (mh1,nh0): read A-h1; stage A-h0(t+2)
    af1[0] = dsr<16384>(aA0); af1[1] = dsr<16384>(aA1);
    af1[2] = dsr<18432>(aA0); af1[3] = dsr<18432>(aA1);
    af1[4] = dsr<20480>(aA0); af1[5] = dsr<20480>(aA1);
    af1[6] = dsr<22528>(aA0); af1[7] = dsr<22528>(aA1);
    if (t + 2 < ktiles) STG_A(0, t + 2, buf);
    __builtin_amdgcn_s_barrier();
    LGKM_SB();
    __builtin_amdgcn_s_setprio(1);
    QMFMA(4, 0, af1, bv0);
    __builtin_amdgcn_s_setprio(0);
    __builtin_amdgcn_s_barrier();
    // ---- p2 (mh0,nh1): read B-n1; stage B-n0(t+2)
    bv1[0] = dsr<49152>(aB0); bv1[1] = dsr<49152>(aB1);
    bv1[2] = dsr<51200>(aB0); bv1[3] = dsr<51200>(aB1);
    if (t + 2 < ktiles) STG_B(0, t + 2, buf);
    __builtin_amdgcn_s_barrier();
    LGKM_SB();
    __builtin_amdgcn_s_setprio(1);
    QMFMA(0, 2, af0, bv1);
    __builtin_amdgcn_s_setprio(0);
    __builtin_amdgcn_s_barrier();
    // ---- p3 (mh1,nh1): no reads; stage A-h1(t+2); counted tile-boundary wait
    if (t + 2 < ktiles) STG_A(1, t + 2, buf);
    __builtin_amdgcn_s_barrier();
    LGKM_SB();
    __builtin_amdgcn_s_setprio(1);
    QMFMA(4, 2, af1, bv1);
    __builtin_amdgcn_s_setprio(0);
    if (t < ktiles - 2)       { asm volatile("s_waitcnt vmcnt(6)" ::: "memory"); }
    else if (t == ktiles - 2) { asm volatile("s_waitcnt vmcnt(0)" ::: "memory"); }
    __builtin_amdgcn_s_barrier();
  }
}

// epilogue: C/D layout col=lane&15, row=(lane>>4)*4+reg
// (derived: quadrant decomposition keeps row = wm*128 + m*16, col = wn*64 + n*16)
__device__ __forceinline__ void ep_f32(float* C, const f32x4 (&acc)[8][4],
                                       int r0, int c0, int ldc, float scale) {
  const int lane = threadIdx.x & 63, w = threadIdx.x >> 6;
  const int crow0 = r0 + (w >> 2) * 128 + ((lane >> 4) << 2);
  const int ccol0 = c0 + (w & 3) * 64 + (lane & 15);
#pragma unroll
  for (int m = 0; m < 8; ++m)
#pragma unroll
    for (int n = 0; n < 4; ++n)
#pragma unroll
      for (int j = 0; j < 4; ++j)
        C[(size_t)(crow0 + m * 16 + j) * ldc + (ccol0 + n * 16)] =
            acc[m][n][j] * scale;
}

__device__ __forceinline__ void ep_bf16(unsigned short* C, const f32x4 (&acc)[8][4],
                                        int r0, int c0, int ldc) {
  const int lane = threadIdx.x & 63, w = threadIdx.x >> 6;
  const int crow0 = r0 + (w >> 2) * 128 + ((lane >> 4) << 2);
  const int ccol0 = c0 + (w & 3) * 64 + (lane & 15);
#pragma unroll
  for (int m = 0; m < 8; ++m)
#pragma unroll
    for (int n = 0; n < 4; ++n)
#pragma unroll
      for (int j = 0; j < 4; ++j)
        C[(size_t)(crow0 + m * 16 + j) * ldc + (ccol0 + n * 16)] =
            f2bf(acc[m][n][j]);
}

// ---------------- kernels ----------------------------------------------------
__global__ __launch_bounds__(512, 2)
void proj_qk(const unsigned short* __restrict__ xb,
             const unsigned short* __restrict__ wqb,
             const unsigned short* __restrict__ wkb,
             unsigned short* __restrict__ Q, unsigned short* __restrict__ Kb) {
  __shared__ __align__(16) unsigned short lds[65536];
  const int bid = blockIdx.x;
  const int wg = (bid & 7) * 32 + (bid >> 3);   // XCD-contiguous chunks
  const int bm = wg >> 4, bnr = wg & 15;
  const unsigned short* B = (bnr < 8) ? wqb : wkb;
  unsigned short* C = (bnr < 8) ? Q : Kb;
  const int bnl = bnr & 7;
  f32x4 acc[8][4];
  gemm_core<2048>(xb + (size_t)bm * 256 * 2048, B + (size_t)bnl * 256 * 2048,
                  lds, 32, acc);
  ep_bf16(C, acc, bm * 256, bnl * 256, 2048);
}

__global__ __launch_bounds__(512, 2)
void vt_qkt(const unsigned short* __restrict__ Qp,
            const unsigned short* __restrict__ Kp,
            const unsigned short* __restrict__ wvb,
            const unsigned short* __restrict__ xb,
            float* __restrict__ sc, unsigned short* __restrict__ Vt,
            float scale) {
  __shared__ __align__(16) unsigned short lds[65536];
  const int id = blockIdx.x;
  const unsigned short *Ab, *Bb;
  int r0, c0;
  bool isq;
  if (id < 136) {
    int bm = 0;
    while ((bm + 1) * (bm + 2) / 2 <= id) ++bm;
    const int bn = id - bm * (bm + 1) / 2;
    Ab = Qp + (size_t)bm * 256 * 2048; Bb = Kp + (size_t)bn * 256 * 2048;
    r0 = bm * 256; c0 = bn * 256; isq = true;
  } else {
    const int v = id - 136, bm = v >> 4, bn = v & 15;
    Ab = wvb + (size_t)bm * 256 * 2048; Bb = xb + (size_t)bn * 256 * 2048;
    r0 = bm * 256; c0 = bn * 256; isq = false;
  }
  f32x4 acc[8][4];
  gemm_core<2048>(Ab, Bb, lds, 32, acc);
  if (isq) ep_f32(sc, acc, r0, c0, 4096, scale);
  else     ep_bf16(Vt, acc, r0, c0, 4096);
}

__global__ __launch_bounds__(512, 2)
void pv(const unsigned short* __restrict__ P,
        const unsigned short* __restrict__ Vt, float* __restrict__ out) {
  __shared__ __align__(16) unsigned short lds[65536];
  const int bn = blockIdx.x, bm = blockIdx.y;
  int kt = (bm + 1) * 4;
  if (kt > 64) kt = 64;
  f32x4 acc[8][4];
  gemm_core<4096>(P + (size_t)bm * 256 * 4096, Vt + (size_t)bn * 256 * 4096,
                  lds, kt, acc);
  ep_f32(out, acc, bm * 256, bn * 256, 2048, 1.0f);
}

// ---------------- causal row softmax: scores f32 -> P bf16 ------------------
__global__ void softmax_causal(const float* __restrict__ Sc,
                               unsigned short* __restrict__ P, int S) {
  const int i = blockIdx.x;
  const int tid = threadIdx.x;
  const int nvalid = i + 1;
  const int pad_end = ((i >> 8) + 1) << 8;   // 256-tile boundary
  const float* row = Sc + (size_t)i * S;

  float v[16];
  float m = -1e30f;
#pragma unroll
  for (int it = 0; it < 16; ++it) {
    const int j = tid + it * 256;
    const float x = (j < nvalid) ? row[j] : -1e30f;
    v[it] = x;
    m = fmaxf(m, x);
  }
#pragma unroll
  for (int d = 1; d < 64; d <<= 1) m = fmaxf(m, __shfl_xor(m, d));
  __shared__ float red_m[4], red_s[4];
  const int lane = tid & 63, wv = tid >> 6;
  if (lane == 0) red_m[wv] = m;
  __syncthreads();
  m = fmaxf(fmaxf(red_m[0], red_m[1]), fmaxf(red_m[2], red_m[3]));

  float s = 0.0f;
#pragma unroll
  for (int it = 0; it < 16; ++it) {
    const int j = tid + it * 256;
    const float e = (j < nvalid) ? __expf(v[it] - m) : 0.0f;
    v[it] = e;
    s += e;
  }
#pragma unroll
  for (int d = 1; d < 64; d <<= 1) s += __shfl_xor(s, d);
  if (lane == 0) red_s[wv] = s;
  __syncthreads();
  s = red_s[0] + red_s[1] + red_s[2] + red_s[3];

  const float inv = 1.0f / s;
  unsigned short* prow = P + (size_t)i * S;
#pragma unroll
  for (int it = 0; it < 16; ++it) {
    const int j = tid + it * 256;
    if (j < pad_end) prow[j] = (j < nvalid) ? f2bf(v[it] * inv) : (unsigned short)0;
  }
}

// ---------------- launch -----------------------------------------------------
extern "C" void kernel_launch(void* const* d_in, const int* in_sizes, int n_in,
                              void* d_out, int out_size, void* d_ws, size_t ws_size,
                              hipStream_t stream) {
  const float* x  = (const float*)d_in[0];
  const float* Wq = (const float*)d_in[1];
  const float* Wk = (const float*)d_in[2];
  const float* Wv = (const float*)d_in[3];
  float* out = (float*)d_out;

  const int S = 4096, D = 2048;
  char* ws = (char*)d_ws;
  const size_t MB = 1u << 20;
  // Workspace (max 136 MiB):
  //   sc  [  0, 64)  f32 scores           live: vt_qkt .. softmax
  //   xb  [ 64, 80)  bf16 x               live: cvt .. vt_qkt
  //   wqb [ 80, 88)  wkb [88,96)          live: cvt .. proj_qk
  //   wvb [ 96,104)                       live: cvt .. vt_qkt
  //   Q   [104,120)  Kb  [120,136)        live: proj_qk .. vt_qkt
  //   Vt  [ 80, 96)  (over wqb/wkb, dead) live: vt_qkt .. pv
  //   P   [104,136)  (over Q/Kb, dead)    live: softmax .. pv
  float*          sc  = (float*)ws;
  unsigned short* xb  = (unsigned short*)(ws + 64 * MB);
  unsigned short* wqb = (unsigned short*)(ws + 80 * MB);
  unsigned short* wkb = (unsigned short*)(ws + 88 * MB);
  unsigned short* wvb = (unsigned short*)(ws + 96 * MB);
  unsigned short* Q   = (unsigned short*)(ws + 104 * MB);
  unsigned short* Kb  = (unsigned short*)(ws + 120 * MB);
  unsigned short* Vt  = (unsigned short*)(ws + 80 * MB);
  unsigned short* P   = (unsigned short*)(ws + 104 * MB);

  cvt_f32_bf16<<<(S * D) / (256 * 8), 256, 0, stream>>>(x, xb, S * D);
  cvt_f32_bf16<<<(D * D) / (256 * 8), 256, 0, stream>>>(Wq, wqb, D * D);
  cvt_f32_bf16<<<(D * D) / (256 * 8), 256, 0, stream>>>(Wk, wkb, D * D);
  cvt_f32_bf16<<<(D * D) / (256 * 8), 256, 0, stream>>>(Wv, wvb, D * D);

  proj_qk<<<256, 512, 0, stream>>>(xb, wqb, wkb, Q, Kb);

  const float scale = 1.0f / sqrtf((float)D);
  vt_qkt<<<264, 512, 0, stream>>>(Q, Kb, wvb, xb, sc, Vt, scale);

  softmax_causal<<<S, 256, 0, stream>>>(sc, P, S);

  pv<<<dim3(8, 16), 512, 0, stream>>>(P, Vt, out);
}

// Round 6
// 246.739 us; speedup vs baseline: 1.3967x; 1.2410x over previous
//
#include <hip/hip_runtime.h>
#include <hip/hip_bf16.h>
#include <math.h>

// S=4096, D=2048. out = causal_softmax((xWq^T)(xWk^T)^T / sqrt(D)) @ (xWv^T)
// R6: same verified gemm_core (counted-vmcnt pipeline); work-rebalanced grids.
//  - vt_qkt: 312 jobs (64 x 8-tile K-chunks of the bm=15 QKT row, atomicAdd
//    into pre-zeroed sc; then 120 full QKT + 128 Vt). Chunks first -> no
//    1-block/CU straggler tail.
//  - pv: 256 jobs (every (bm,bn) split half-K); half0 -> out, half1 -> aux;
//    final add kernel. Makespan 64 -> 32 K-tiles.

typedef __attribute__((ext_vector_type(8))) short bf16x8;
typedef __attribute__((ext_vector_type(4))) float f32x4;
typedef __attribute__((ext_vector_type(8))) unsigned short u16x8;
typedef __attribute__((ext_vector_type(4))) int iv4;

__device__ __forceinline__ unsigned short f2bf(float f) {
  unsigned int u = __float_as_uint(f);
  u += 0x7FFFu + ((u >> 16) & 1u);   // RNE
  return (unsigned short)(u >> 16);
}

__device__ __forceinline__ void gload16(const unsigned short* g, unsigned short* l) {
  __builtin_amdgcn_global_load_lds(
      (const __attribute__((address_space(1))) void*)g,
      (__attribute__((address_space(3))) void*)l,
      16, 0, 0);
}

template <int OFF>
__device__ __forceinline__ bf16x8 dsr(unsigned addr) {
  iv4 r;
  asm volatile("ds_read_b128 %0, %1 offset:%2" : "=v"(r) : "v"(addr), "i"(OFF));
  return __builtin_bit_cast(bf16x8, r);
}

// ---------------- f32 -> bf16 convert ---------------------------------------
__global__ void cvt_f32_bf16(const float* __restrict__ in,
                             unsigned short* __restrict__ out, int n) {
  int i = (blockIdx.x * 256 + threadIdx.x) * 8;
  if (i >= n) return;
  float4 a = *(const float4*)(in + i);
  float4 b = *(const float4*)(in + i + 4);
  u16x8 r;
  r[0] = f2bf(a.x); r[1] = f2bf(a.y); r[2] = f2bf(a.z); r[3] = f2bf(a.w);
  r[4] = f2bf(b.x); r[5] = f2bf(b.y); r[6] = f2bf(b.z); r[7] = f2bf(b.w);
  *(u16x8*)(out + i) = r;
}

// ---------------- 256x256 GEMM core (counted-vmcnt pipeline) -----------------
// Unchanged from R5 (verified): BK=64, 512 thr = 8 waves (2Mx4N), LDS 128KB =
// 2 bufs x {A:2, B:2} x 16KB units; quadrant phases w/ read-once frag reuse;
// stage units rotate 3-in-flight; vmcnt(6) once per tile. K-offset jobs pass
// pre-advanced Ab/Bb pointers (row stride KC unchanged).
#define LGKM_SB()                                         \
  asm volatile("s_waitcnt lgkmcnt(0)" ::: "memory");      \
  __builtin_amdgcn_sched_barrier(0)

#define QMFMA(MB, NB, AF, BV)                                                 \
  _Pragma("unroll")                                                           \
  for (int _fm = 0; _fm < 4; ++_fm)                                           \
    _Pragma("unroll")                                                         \
    for (int _fn = 0; _fn < 2; ++_fn)                                         \
      _Pragma("unroll")                                                       \
      for (int _ks = 0; _ks < 2; ++_ks)                                       \
        acc[(MB) + _fm][(NB) + _fn] = __builtin_amdgcn_mfma_f32_16x16x32_bf16( \
            AF[_fm * 2 + _ks], BV[_fn * 2 + _ks], acc[(MB) + _fm][(NB) + _fn], \
            0, 0, 0);

#define STG_A(mhv, tau, bufv)                                                 \
  do {                                                                        \
    unsigned short* _d = lds + (bufv) * 32768 + (mhv) * 8192 + w * 512;       \
    gload16(pA + (size_t)((mhv) * 64) * KC + ((size_t)(tau) << 6), _d);       \
    gload16(pA + (size_t)(128 + (mhv) * 64) * KC + ((size_t)(tau) << 6),      \
            _d + 4096);                                                       \
  } while (0)

#define STG_B(nhv, tau, bufv)                                                 \
  do {                                                                        \
    unsigned short* _d = lds + (bufv) * 32768 + 16384 + (nhv) * 8192 + w * 512;\
    gload16(pB + (size_t)((nhv) * 32) * KC + ((size_t)(tau) << 6), _d);       \
    gload16(pB + (size_t)(128 + (nhv) * 32) * KC + ((size_t)(tau) << 6),      \
            _d + 4096);                                                       \
  } while (0)

template <int KC>
__device__ __forceinline__ void gemm_core(const unsigned short* __restrict__ Ab,
                                          const unsigned short* __restrict__ Bb,
                                          unsigned short* lds, int ktiles,
                                          f32x4 (&acc)[8][4]) {
  const int tid  = threadIdx.x;
  const int lane = tid & 63;
  const int w    = tid >> 6;          // 0..7
  const int wm   = w >> 2;            // 0..1
  const int wn   = w & 3;             // 0..3

  const int base  = w * 8 + (lane >> 3);           // 0..63
  const int gslot = (lane & 7) ^ ((lane >> 3) & 7);
  const unsigned short* pA = Ab + (size_t)base * KC + gslot * 8;
  const unsigned short* pB =
      Bb + (size_t)((base >> 5) * 64 + (base & 31)) * KC + gslot * 8;

  const unsigned lb = (unsigned)(size_t)&lds[0];
  const int rl = lane & 15, g = lane >> 4;
  const unsigned sw0 = (unsigned)(((0 + g) ^ (rl & 7)) * 16);
  const unsigned sw1 = (unsigned)(((4 + g) ^ (rl & 7)) * 16);
  const unsigned rA = lb + (unsigned)(wm * 8192 + rl * 128);
  const unsigned rB = lb + (unsigned)(wn * 4096 + rl * 128);

#pragma unroll
  for (int m = 0; m < 8; ++m)
#pragma unroll
    for (int n = 0; n < 4; ++n) acc[m][n] = f32x4{0.f, 0.f, 0.f, 0.f};

  STG_A(0, 0, 0); STG_B(0, 0, 0); STG_A(1, 0, 0); STG_B(1, 0, 0);
  STG_A(0, 1, 1); STG_B(0, 1, 1); STG_A(1, 1, 1);
  asm volatile("s_waitcnt vmcnt(6)" ::: "memory");
  __builtin_amdgcn_s_barrier();

  for (int t = 0; t < ktiles; ++t) {
    const unsigned bo = (unsigned)(t & 1) << 16;
    const int buf = t & 1, nb = (t + 1) & 1;
    const unsigned aA0 = rA + bo + sw0, aA1 = rA + bo + sw1;
    const unsigned aB0 = rB + bo + sw0, aB1 = rB + bo + sw1;
    bf16x8 af0[8], af1[8], bv0[4], bv1[4];
    // ---- p0 (mh0,nh0): read A-h0 + B-n0; stage B-n1(t+1)
    af0[0] = dsr<0>(aA0);     af0[1] = dsr<0>(aA1);
    af0[2] = dsr<2048>(aA0);  af0[3] = dsr<2048>(aA1);
    af0[4] = dsr<4096>(aA0);  af0[5] = dsr<4096>(aA1);
    af0[6] = dsr<6144>(aA0);  af0[7] = dsr<6144>(aA1);
    bv0[0] = dsr<32768>(aB0); bv0[1] = dsr<32768>(aB1);
    bv0[2] = dsr<34816>(aB0); bv0[3] = dsr<34816>(aB1);
    if (t + 1 < ktiles) STG_B(1, t + 1, nb);
    __builtin_amdgcn_s_barrier();
    LGKM_SB();
    __builtin_amdgcn_s_setprio(1);
    QMFMA(0, 0, af0, bv0);
    __builtin_amdgcn_s_setprio(0);
    __builtin_amdgcn_s_barrier();
    // ---- p1 (mh1,nh0): read A-h1; stage A-h0(t+2)
    af1[0] = dsr<16384>(aA0); af1[1] = dsr<16384>(aA1);
    af1[2] = dsr<18432>(aA0); af1[3] = dsr<18432>(aA1);
    af1[4] = dsr<20480>(aA0); af1[5] = dsr<20480>(aA1);
    af1[6] = dsr<22528>(aA0); af1[7] = dsr<22528>(aA1);
    if (t + 2 < ktiles) STG_A(0, t + 2, buf);
    __builtin_amdgcn_s_barrier();
    LGKM_SB();
    __builtin_amdgcn_s_setprio(1);
    QMFMA(4, 0, af1, bv0);
    __builtin_amdgcn_s_setprio(0);
    __builtin_amdgcn_s_barrier();
    // ---- p2 (mh0,nh1): read B-n1; stage B-n0(t+2)
    bv1[0] = dsr<49152>(aB0); bv1[1] = dsr<49152>(aB1);
    bv1[2] = dsr<51200>(aB0); bv1[3] = dsr<51200>(aB1);
    if (t + 2 < ktiles) STG_B(0, t + 2, buf);
    __builtin_amdgcn_s_barrier();
    LGKM_SB();
    __builtin_amdgcn_s_setprio(1);
    QMFMA(0, 2, af0, bv1);
    __builtin_amdgcn_s_setprio(0);
    __builtin_amdgcn_s_barrier();
    // ---- p3 (mh1,nh1): no reads; stage A-h1(t+2); counted tile-boundary wait
    if (t + 2 < ktiles) STG_A(1, t + 2, buf);
    __builtin_amdgcn_s_barrier();
    LGKM_SB();
    __builtin_amdgcn_s_setprio(1);
    QMFMA(4, 2, af1, bv1);
    __builtin_amdgcn_s_setprio(0);
    if (t < ktiles - 2)       { asm volatile("s_waitcnt vmcnt(6)" ::: "memory"); }
    else if (t == ktiles - 2) { asm volatile("s_waitcnt vmcnt(0)" ::: "memory"); }
    __builtin_amdgcn_s_barrier();
  }
}

// epilogues: C/D layout col=lane&15, row=(lane>>4)*4+reg
__device__ __forceinline__ void ep_f32(float* C, const f32x4 (&acc)[8][4],
                                       int r0, int c0, int ldc, float scale) {
  const int lane = threadIdx.x & 63, w = threadIdx.x >> 6;
  const int crow0 = r0 + (w >> 2) * 128 + ((lane >> 4) << 2);
  const int ccol0 = c0 + (w & 3) * 64 + (lane & 15);
#pragma unroll
  for (int m = 0; m < 8; ++m)
#pragma unroll
    for (int n = 0; n < 4; ++n)
#pragma unroll
      for (int j = 0; j < 4; ++j)
        C[(size_t)(crow0 + m * 16 + j) * ldc + (ccol0 + n * 16)] =
            acc[m][n][j] * scale;
}

__device__ __forceinline__ void ep_f32_at(float* C, const f32x4 (&acc)[8][4],
                                          int r0, int c0, int ldc, float scale) {
  const int lane = threadIdx.x & 63, w = threadIdx.x >> 6;
  const int crow0 = r0 + (w >> 2) * 128 + ((lane >> 4) << 2);
  const int ccol0 = c0 + (w & 3) * 64 + (lane & 15);
#pragma unroll
  for (int m = 0; m < 8; ++m)
#pragma unroll
    for (int n = 0; n < 4; ++n)
#pragma unroll
      for (int j = 0; j < 4; ++j)
        atomicAdd(&C[(size_t)(crow0 + m * 16 + j) * ldc + (ccol0 + n * 16)],
                  acc[m][n][j] * scale);
}

__device__ __forceinline__ void ep_bf16(unsigned short* C, const f32x4 (&acc)[8][4],
                                        int r0, int c0, int ldc) {
  const int lane = threadIdx.x & 63, w = threadIdx.x >> 6;
  const int crow0 = r0 + (w >> 2) * 128 + ((lane >> 4) << 2);
  const int ccol0 = c0 + (w & 3) * 64 + (lane & 15);
#pragma unroll
  for (int m = 0; m < 8; ++m)
#pragma unroll
    for (int n = 0; n < 4; ++n)
#pragma unroll
      for (int j = 0; j < 4; ++j)
        C[(size_t)(crow0 + m * 16 + j) * ldc + (ccol0 + n * 16)] =
            f2bf(acc[m][n][j]);
}

// ---------------- kernels ----------------------------------------------------
__global__ __launch_bounds__(512, 2)
void proj_qk(const unsigned short* __restrict__ xb,
             const unsigned short* __restrict__ wqb,
             const unsigned short* __restrict__ wkb,
             unsigned short* __restrict__ Q, unsigned short* __restrict__ Kb) {
  __shared__ __align__(16) unsigned short lds[65536];
  const int bid = blockIdx.x;
  const int wg = (bid & 7) * 32 + (bid >> 3);   // XCD-contiguous chunks
  const int bm = wg >> 4, bnr = wg & 15;
  const unsigned short* B = (bnr < 8) ? wqb : wkb;
  unsigned short* C = (bnr < 8) ? Q : Kb;
  const int bnl = bnr & 7;
  f32x4 acc[8][4];
  gemm_core<2048>(xb + (size_t)bm * 256 * 2048, B + (size_t)bnl * 256 * 2048,
                  lds, 32, acc);
  ep_bf16(C, acc, bm * 256, bnl * 256, 2048);
}

// 312 jobs: [0,64): bm=15 QKT K-chunks (8 tiles, atomicAdd into zeroed sc);
//           [64,184): full QKT bm=0..14 lower-triangle; [184,312): Vt tiles.
__global__ __launch_bounds__(512, 2)
void vt_qkt(const unsigned short* __restrict__ Qp,
            const unsigned short* __restrict__ Kp,
            const unsigned short* __restrict__ wvb,
            const unsigned short* __restrict__ xb,
            float* __restrict__ sc, unsigned short* __restrict__ Vt,
            float scale) {
  __shared__ __align__(16) unsigned short lds[65536];
  const int id = blockIdx.x;
  f32x4 acc[8][4];
  if (id < 64) {
    const int p = id >> 2, c = id & 3;       // parent (15,p), K-chunk c
    const size_t koff = (size_t)c * 8 * 64;
    gemm_core<2048>(Qp + (size_t)15 * 256 * 2048 + koff,
                    Kp + (size_t)p * 256 * 2048 + koff, lds, 8, acc);
    ep_f32_at(sc, acc, 3840, p * 256, 4096, scale);
  } else if (id < 184) {
    const int q = id - 64;
    int bm = 0;
    while ((bm + 1) * (bm + 2) / 2 <= q) ++bm;
    const int bn = q - bm * (bm + 1) / 2;
    gemm_core<2048>(Qp + (size_t)bm * 256 * 2048,
                    Kp + (size_t)bn * 256 * 2048, lds, 32, acc);
    ep_f32(sc, acc, bm * 256, bn * 256, 4096, scale);
  } else {
    const int v = id - 184, bm = v >> 4, bn = v & 15;
    gemm_core<2048>(wvb + (size_t)bm * 256 * 2048,
                    xb + (size_t)bn * 256 * 2048, lds, 32, acc);
    ep_bf16(Vt, acc, bm * 256, bn * 256, 4096);
  }
}

// PV half-K split: 256 jobs; half0 -> out, half1 -> aux; out += aux later.
__global__ __launch_bounds__(512, 2)
void pv(const unsigned short* __restrict__ P,
        const unsigned short* __restrict__ Vt, float* __restrict__ out,
        float* __restrict__ aux) {
  __shared__ __align__(16) unsigned short lds[65536];
  const int id = blockIdx.x;
  const int j = id >> 1, h = id & 1;
  const int bm = j >> 3, bn = j & 7;
  const int kt = (bm + 1) * 4;
  const int k0 = h ? (kt >> 1) : 0;
  const int ktl = h ? (kt - (kt >> 1)) : (kt >> 1);
  f32x4 acc[8][4];
  gemm_core<4096>(P + (size_t)bm * 256 * 4096 + (size_t)k0 * 64,
                  Vt + (size_t)bn * 256 * 4096 + (size_t)k0 * 64, lds, ktl, acc);
  if (h) ep_f32(aux, acc, bm * 256, bn * 256, 2048, 1.0f);
  else   ep_f32(out, acc, bm * 256, bn * 256, 2048, 1.0f);
}

__global__ void add_f32(float* __restrict__ out, const float* __restrict__ aux,
                        int n) {
  int i = (blockIdx.x * 256 + threadIdx.x) * 8;
  if (i >= n) return;
  float4 a0 = *(const float4*)(out + i), a1 = *(const float4*)(out + i + 4);
  float4 b0 = *(const float4*)(aux + i), b1 = *(const float4*)(aux + i + 4);
  a0.x += b0.x; a0.y += b0.y; a0.z += b0.z; a0.w += b0.w;
  a1.x += b1.x; a1.y += b1.y; a1.z += b1.z; a1.w += b1.w;
  *(float4*)(out + i) = a0; *(float4*)(out + i + 4) = a1;
}

// ---------------- causal row softmax: scores f32 -> P bf16 ------------------
__global__ void softmax_causal(const float* __restrict__ Sc,
                               unsigned short* __restrict__ P, int S) {
  const int i = blockIdx.x;
  const int tid = threadIdx.x;
  const int nvalid = i + 1;
  const int pad_end = ((i >> 8) + 1) << 8;   // 256-tile boundary
  const float* row = Sc + (size_t)i * S;

  float v[16];
  float m = -1e30f;
#pragma unroll
  for (int it = 0; it < 16; ++it) {
    const int j = tid + it * 256;
    const float x = (j < nvalid) ? row[j] : -1e30f;
    v[it] = x;
    m = fmaxf(m, x);
  }
#pragma unroll
  for (int d = 1; d < 64; d <<= 1) m = fmaxf(m, __shfl_xor(m, d));
  __shared__ float red_m[4], red_s[4];
  const int lane = tid & 63, wv = tid >> 6;
  if (lane == 0) red_m[wv] = m;
  __syncthreads();
  m = fmaxf(fmaxf(red_m[0], red_m[1]), fmaxf(red_m[2], red_m[3]));

  float s = 0.0f;
#pragma unroll
  for (int it = 0; it < 16; ++it) {
    const int j = tid + it * 256;
    const float e = (j < nvalid) ? __expf(v[it] - m) : 0.0f;
    v[it] = e;
    s += e;
  }
#pragma unroll
  for (int d = 1; d < 64; d <<= 1) s += __shfl_xor(s, d);
  if (lane == 0) red_s[wv] = s;
  __syncthreads();
  s = red_s[0] + red_s[1] + red_s[2] + red_s[3];

  const float inv = 1.0f / s;
  unsigned short* prow = P + (size_t)i * S;
#pragma unroll
  for (int it = 0; it < 16; ++it) {
    const int j = tid + it * 256;
    if (j < pad_end) prow[j] = (j < nvalid) ? f2bf(v[it] * inv) : (unsigned short)0;
  }
}

// ---------------- launch -----------------------------------------------------
extern "C" void kernel_launch(void* const* d_in, const int* in_sizes, int n_in,
                              void* d_out, int out_size, void* d_ws, size_t ws_size,
                              hipStream_t stream) {
  const float* x  = (const float*)d_in[0];
  const float* Wq = (const float*)d_in[1];
  const float* Wk = (const float*)d_in[2];
  const float* Wv = (const float*)d_in[3];
  float* out = (float*)d_out;

  const int S = 4096, D = 2048;
  char* ws = (char*)d_ws;
  const size_t MB = 1u << 20;
  // Workspace (peak 136 MiB):
  //   sc  [  0, 64)  f32 scores            live: vt_qkt .. softmax
  //   aux [  0, 32)  pv half1 (over sc)    live: pv .. add
  //   xb  [ 64, 80)                        live: cvt .. vt_qkt
  //   wqb [ 80, 88)  wkb [88,96)           live: cvt .. proj_qk
  //   wvb [ 96,104)                        live: cvt .. vt_qkt
  //   Q   [104,120)  Kb [120,136)          live: proj_qk .. vt_qkt
  //   Vt  [ 80, 96)  (over wqb/wkb)        live: vt_qkt .. pv
  //   P   [104,136)  (over Q/Kb)           live: softmax .. pv
  float*          sc  = (float*)ws;
  float*          aux = (float*)ws;
  unsigned short* xb  = (unsigned short*)(ws + 64 * MB);
  unsigned short* wqb = (unsigned short*)(ws + 80 * MB);
  unsigned short* wkb = (unsigned short*)(ws + 88 * MB);
  unsigned short* wvb = (unsigned short*)(ws + 96 * MB);
  unsigned short* Q   = (unsigned short*)(ws + 104 * MB);
  unsigned short* Kb  = (unsigned short*)(ws + 120 * MB);
  unsigned short* Vt  = (unsigned short*)(ws + 80 * MB);
  unsigned short* P   = (unsigned short*)(ws + 104 * MB);

  cvt_f32_bf16<<<(S * D) / (256 * 8), 256, 0, stream>>>(x, xb, S * D);
  cvt_f32_bf16<<<(D * D) / (256 * 8), 256, 0, stream>>>(Wq, wqb, D * D);
  cvt_f32_bf16<<<(D * D) / (256 * 8), 256, 0, stream>>>(Wk, wkb, D * D);
  cvt_f32_bf16<<<(D * D) / (256 * 8), 256, 0, stream>>>(Wv, wvb, D * D);

  proj_qk<<<256, 512, 0, stream>>>(xb, wqb, wkb, Q, Kb);

  // zero sc rows 3840..4095 (atomicAdd targets of the K-chunk jobs)
  hipMemsetAsync(sc + (size_t)3840 * 4096, 0, (size_t)256 * 4096 * 4, stream);

  const float scale = 1.0f / sqrtf((float)D);
  vt_qkt<<<312, 512, 0, stream>>>(Q, Kb, wvb, xb, sc, Vt, scale);

  softmax_causal<<<S, 256, 0, stream>>>(sc, P, S);

  pv<<<256, 512, 0, stream>>>(P, Vt, out, aux);
  add_f32<<<(S * D) / (256 * 8), 256, 0, stream>>>(out, aux, S * D);
}

// Round 7
// 240.026 us; speedup vs baseline: 1.4357x; 1.0280x over previous
//
#include <hip/hip_runtime.h>
#include <hip/hip_bf16.h>
#include <math.h>

// S=4096, D=2048. out = causal_softmax((xWq^T)(xWk^T)^T / sqrt(D)) @ (xWv^T)
// R7: read-ahead gemm_core — per phase: lgkm -> MFMA -> issue next-phase
// ds_reads -> issue stage -> vmcnt(8) -> barrier. LDS reads hide under MFMA;
// 4 barriers/K-tile (was 8); uniform counted vmcnt(8), >=5-phase stage flight.
// Grids/balancing identical to R6 (isolate the schedule change).

typedef __attribute__((ext_vector_type(8))) short bf16x8;
typedef __attribute__((ext_vector_type(4))) float f32x4;
typedef __attribute__((ext_vector_type(8))) unsigned short u16x8;
typedef __attribute__((ext_vector_type(4))) int iv4;

__device__ __forceinline__ unsigned short f2bf(float f) {
  unsigned int u = __float_as_uint(f);
  u += 0x7FFFu + ((u >> 16) & 1u);   // RNE
  return (unsigned short)(u >> 16);
}

__device__ __forceinline__ void gload16(const unsigned short* g, unsigned short* l) {
  __builtin_amdgcn_global_load_lds(
      (const __attribute__((address_space(1))) void*)g,
      (__attribute__((address_space(3))) void*)l,
      16, 0, 0);
}

template <int OFF>
__device__ __forceinline__ bf16x8 dsr(unsigned addr) {
  iv4 r;
  asm volatile("ds_read_b128 %0, %1 offset:%2" : "=v"(r) : "v"(addr), "i"(OFF));
  return __builtin_bit_cast(bf16x8, r);
}

// ---------------- f32 -> bf16 convert ---------------------------------------
__global__ void cvt_f32_bf16(const float* __restrict__ in,
                             unsigned short* __restrict__ out, int n) {
  int i = (blockIdx.x * 256 + threadIdx.x) * 8;
  if (i >= n) return;
  float4 a = *(const float4*)(in + i);
  float4 b = *(const float4*)(in + i + 4);
  u16x8 r;
  r[0] = f2bf(a.x); r[1] = f2bf(a.y); r[2] = f2bf(a.z); r[3] = f2bf(a.w);
  r[4] = f2bf(b.x); r[5] = f2bf(b.y); r[6] = f2bf(b.z); r[7] = f2bf(b.w);
  *(u16x8*)(out + i) = r;
}

// ---------------- 256x256 GEMM core (read-ahead pipeline) --------------------
// Layout identical to R5/R6 (verified): BK=64, 512 thr = 8 waves (2Mx4N),
// LDS 128KB = 2 bufs x {A:2, B:2} x 16KB units.
// Phase k body: lgkm(0); MFMA(quadrant k); issue next reads; issue stage;
// vmcnt(8); barrier.  Read-issue slots: k0: af1(t); k1: bv1(t);
// k2: af0,bv0(t+1) [2 phases ahead]; k3: none.
// Stage slots: k0: B-n1(t+1); k1: A-h0(t+2)+B-n0(t+2); k2: A-h1(t+2).
// FIFO proof (2 loads/STG, 8 loads/tile): each phase-end vmcnt(8) retires
// exactly the unit the following read-issue needs (see derivation in R7 log).
// WAR: every staged region's prior reads lgkm'd >=1 barrier before the stage.
// Tail t>=kt-2: vmcnt(0). Regs: af0/af1/bv0/bv1 loop-carried, static indices.
#define LGKM_SB()                                         \
  asm volatile("s_waitcnt lgkmcnt(0)" ::: "memory");      \
  __builtin_amdgcn_sched_barrier(0)

#define QMFMA(MB, NB, AF, BV)                                                 \
  _Pragma("unroll")                                                           \
  for (int _fm = 0; _fm < 4; ++_fm)                                           \
    _Pragma("unroll")                                                         \
    for (int _fn = 0; _fn < 2; ++_fn)                                         \
      _Pragma("unroll")                                                       \
      for (int _ks = 0; _ks < 2; ++_ks)                                       \
        acc[(MB) + _fm][(NB) + _fn] = __builtin_amdgcn_mfma_f32_16x16x32_bf16( \
            AF[_fm * 2 + _ks], BV[_fn * 2 + _ks], acc[(MB) + _fm][(NB) + _fn], \
            0, 0, 0);

#define STG_A(mhv, tau, bufv)                                                 \
  do {                                                                        \
    unsigned short* _d = lds + (bufv) * 32768 + (mhv) * 8192 + w * 512;       \
    gload16(pA + (size_t)((mhv) * 64) * KC + ((size_t)(tau) << 6), _d);       \
    gload16(pA + (size_t)(128 + (mhv) * 64) * KC + ((size_t)(tau) << 6),      \
            _d + 4096);                                                       \
  } while (0)

#define STG_B(nhv, tau, bufv)                                                 \
  do {                                                                        \
    unsigned short* _d = lds + (bufv) * 32768 + 16384 + (nhv) * 8192 + w * 512;\
    gload16(pB + (size_t)((nhv) * 32) * KC + ((size_t)(tau) << 6), _d);       \
    gload16(pB + (size_t)(128 + (nhv) * 32) * KC + ((size_t)(tau) << 6),      \
            _d + 4096);                                                       \
  } while (0)

#define VM_WAIT()                                                             \
  do {                                                                        \
    if (tail) { asm volatile("s_waitcnt vmcnt(0)" ::: "memory"); }            \
    else      { asm volatile("s_waitcnt vmcnt(8)" ::: "memory"); }            \
  } while (0)

template <int KC>
__device__ __forceinline__ void gemm_core(const unsigned short* __restrict__ Ab,
                                          const unsigned short* __restrict__ Bb,
                                          unsigned short* lds, int ktiles,
                                          f32x4 (&acc)[8][4]) {
  const int tid  = threadIdx.x;
  const int lane = tid & 63;
  const int w    = tid >> 6;          // 0..7
  const int wm   = w >> 2;            // 0..1
  const int wn   = w & 3;             // 0..3

  const int base  = w * 8 + (lane >> 3);           // 0..63
  const int gslot = (lane & 7) ^ ((lane >> 3) & 7);
  const unsigned short* pA = Ab + (size_t)base * KC + gslot * 8;
  const unsigned short* pB =
      Bb + (size_t)((base >> 5) * 64 + (base & 31)) * KC + gslot * 8;

  const unsigned lb = (unsigned)(size_t)&lds[0];
  const int rl = lane & 15, g = lane >> 4;
  const unsigned sw0 = (unsigned)(((0 + g) ^ (rl & 7)) * 16);
  const unsigned sw1 = (unsigned)(((4 + g) ^ (rl & 7)) * 16);
  const unsigned rA = lb + (unsigned)(wm * 8192 + rl * 128);
  const unsigned rB = lb + (unsigned)(wn * 4096 + rl * 128);

#pragma unroll
  for (int m = 0; m < 8; ++m)
#pragma unroll
    for (int n = 0; n < 4; ++n) acc[m][n] = f32x4{0.f, 0.f, 0.f, 0.f};

  // prologue: t0 fully; t1's A-h0,B-n0,A-h1 (B-n1(1) staged in-loop at k0(0))
  STG_A(0, 0, 0); STG_B(0, 0, 0); STG_A(1, 0, 0); STG_B(1, 0, 0);
  if (ktiles > 1) {
    STG_A(0, 1, 1); STG_B(0, 1, 1); STG_A(1, 1, 1);
    asm volatile("s_waitcnt vmcnt(6)" ::: "memory");
  } else {
    asm volatile("s_waitcnt vmcnt(0)" ::: "memory");
  }
  __builtin_amdgcn_s_barrier();

  bf16x8 af0[8], af1[8], bv0[4], bv1[4];
  {  // prime t0's (mh0,nh0) operands
    const unsigned aA0 = rA + sw0, aA1 = rA + sw1;
    const unsigned aB0 = rB + sw0, aB1 = rB + sw1;
    af0[0] = dsr<0>(aA0);     af0[1] = dsr<0>(aA1);
    af0[2] = dsr<2048>(aA0);  af0[3] = dsr<2048>(aA1);
    af0[4] = dsr<4096>(aA0);  af0[5] = dsr<4096>(aA1);
    af0[6] = dsr<6144>(aA0);  af0[7] = dsr<6144>(aA1);
    bv0[0] = dsr<32768>(aB0); bv0[1] = dsr<32768>(aB1);
    bv0[2] = dsr<34816>(aB0); bv0[3] = dsr<34816>(aB1);
  }

  for (int t = 0; t < ktiles; ++t) {
    const unsigned bo  = (unsigned)(t & 1) << 16;
    const unsigned bon = (unsigned)((t + 1) & 1) << 16;
    const int buf = t & 1, nb = (t + 1) & 1;
    const bool s1 = (t + 1) < ktiles, s2 = (t + 2) < ktiles;
    const bool tail = t >= ktiles - 2;
    const unsigned aA0 = rA + bo + sw0, aA1 = rA + bo + sw1;
    const unsigned aB0 = rB + bo + sw0, aB1 = rB + bo + sw1;
    const unsigned nA0 = rA + bon + sw0, nA1 = rA + bon + sw1;
    const unsigned nB0 = rB + bon + sw0, nB1 = rB + bon + sw1;

    // ---- k0: MFMA(00) | issue af1(t) | stage B-n1(t+1)
    LGKM_SB();
    __builtin_amdgcn_s_setprio(1);
    QMFMA(0, 0, af0, bv0);
    __builtin_amdgcn_s_setprio(0);
    af1[0] = dsr<16384>(aA0); af1[1] = dsr<16384>(aA1);
    af1[2] = dsr<18432>(aA0); af1[3] = dsr<18432>(aA1);
    af1[4] = dsr<20480>(aA0); af1[5] = dsr<20480>(aA1);
    af1[6] = dsr<22528>(aA0); af1[7] = dsr<22528>(aA1);
    if (s1) STG_B(1, t + 1, nb);
    VM_WAIT();
    __builtin_amdgcn_s_barrier();

    // ---- k1: MFMA(10) | issue bv1(t) | stage A-h0(t+2)+B-n0(t+2)
    LGKM_SB();
    __builtin_amdgcn_s_setprio(1);
    QMFMA(4, 0, af1, bv0);
    __builtin_amdgcn_s_setprio(0);
    bv1[0] = dsr<49152>(aB0); bv1[1] = dsr<49152>(aB1);
    bv1[2] = dsr<51200>(aB0); bv1[3] = dsr<51200>(aB1);
    if (s2) { STG_A(0, t + 2, buf); STG_B(0, t + 2, buf); }
    VM_WAIT();
    __builtin_amdgcn_s_barrier();

    // ---- k2: MFMA(01) | issue af0,bv0(t+1) (2 phases ahead) | stage A-h1(t+2)
    LGKM_SB();
    __builtin_amdgcn_s_setprio(1);
    QMFMA(0, 2, af0, bv1);
    __builtin_amdgcn_s_setprio(0);
    if (s1) {
      af0[0] = dsr<0>(nA0);     af0[1] = dsr<0>(nA1);
      af0[2] = dsr<2048>(nA0);  af0[3] = dsr<2048>(nA1);
      af0[4] = dsr<4096>(nA0);  af0[5] = dsr<4096>(nA1);
      af0[6] = dsr<6144>(nA0);  af0[7] = dsr<6144>(nA1);
      bv0[0] = dsr<32768>(nB0); bv0[1] = dsr<32768>(nB1);
      bv0[2] = dsr<34816>(nB0); bv0[3] = dsr<34816>(nB1);
    }
    if (s2) STG_A(1, t + 2, buf);
    VM_WAIT();
    __builtin_amdgcn_s_barrier();

    // ---- k3: MFMA(11) | no reads (af1,bv1 already lgkm'd; cross reads stay
    //      in flight past this phase — no lgkm here by design)
    __builtin_amdgcn_sched_barrier(0);
    __builtin_amdgcn_s_setprio(1);
    QMFMA(4, 2, af1, bv1);
    __builtin_amdgcn_s_setprio(0);
    VM_WAIT();
    __builtin_amdgcn_s_barrier();
  }
}

// epilogues: C/D layout col=lane&15, row=(lane>>4)*4+reg
__device__ __forceinline__ void ep_f32(float* C, const f32x4 (&acc)[8][4],
                                       int r0, int c0, int ldc, float scale) {
  const int lane = threadIdx.x & 63, w = threadIdx.x >> 6;
  const int crow0 = r0 + (w >> 2) * 128 + ((lane >> 4) << 2);
  const int ccol0 = c0 + (w & 3) * 64 + (lane & 15);
#pragma unroll
  for (int m = 0; m < 8; ++m)
#pragma unroll
    for (int n = 0; n < 4; ++n)
#pragma unroll
      for (int j = 0; j < 4; ++j)
        C[(size_t)(crow0 + m * 16 + j) * ldc + (ccol0 + n * 16)] =
            acc[m][n][j] * scale;
}

__device__ __forceinline__ void ep_f32_at(float* C, const f32x4 (&acc)[8][4],
                                          int r0, int c0, int ldc, float scale) {
  const int lane = threadIdx.x & 63, w = threadIdx.x >> 6;
  const int crow0 = r0 + (w >> 2) * 128 + ((lane >> 4) << 2);
  const int ccol0 = c0 + (w & 3) * 64 + (lane & 15);
#pragma unroll
  for (int m = 0; m < 8; ++m)
#pragma unroll
    for (int n = 0; n < 4; ++n)
#pragma unroll
      for (int j = 0; j < 4; ++j)
        atomicAdd(&C[(size_t)(crow0 + m * 16 + j) * ldc + (ccol0 + n * 16)],
                  acc[m][n][j] * scale);
}

__device__ __forceinline__ void ep_bf16(unsigned short* C, const f32x4 (&acc)[8][4],
                                        int r0, int c0, int ldc) {
  const int lane = threadIdx.x & 63, w = threadIdx.x >> 6;
  const int crow0 = r0 + (w >> 2) * 128 + ((lane >> 4) << 2);
  const int ccol0 = c0 + (w & 3) * 64 + (lane & 15);
#pragma unroll
  for (int m = 0; m < 8; ++m)
#pragma unroll
    for (int n = 0; n < 4; ++n)
#pragma unroll
      for (int j = 0; j < 4; ++j)
        C[(size_t)(crow0 + m * 16 + j) * ldc + (ccol0 + n * 16)] =
            f2bf(acc[m][n][j]);
}

// ---------------- kernels ----------------------------------------------------
__global__ __launch_bounds__(512, 2)
void proj_qk(const unsigned short* __restrict__ xb,
             const unsigned short* __restrict__ wqb,
             const unsigned short* __restrict__ wkb,
             unsigned short* __restrict__ Q, unsigned short* __restrict__ Kb) {
  __shared__ __align__(16) unsigned short lds[65536];
  const int bid = blockIdx.x;
  const int wg = (bid & 7) * 32 + (bid >> 3);   // XCD-contiguous chunks
  const int bm = wg >> 4, bnr = wg & 15;
  const unsigned short* B = (bnr < 8) ? wqb : wkb;
  unsigned short* C = (bnr < 8) ? Q : Kb;
  const int bnl = bnr & 7;
  f32x4 acc[8][4];
  gemm_core<2048>(xb + (size_t)bm * 256 * 2048, B + (size_t)bnl * 256 * 2048,
                  lds, 32, acc);
  ep_bf16(C, acc, bm * 256, bnl * 256, 2048);
}

// 312 jobs: [0,64): bm=15 QKT K-chunks (8 tiles, atomicAdd into zeroed sc);
//           [64,184): full QKT bm=0..14 lower-triangle; [184,312): Vt tiles.
__global__ __launch_bounds__(512, 2)
void vt_qkt(const unsigned short* __restrict__ Qp,
            const unsigned short* __restrict__ Kp,
            const unsigned short* __restrict__ wvb,
            const unsigned short* __restrict__ xb,
            float* __restrict__ sc, unsigned short* __restrict__ Vt,
            float scale) {
  __shared__ __align__(16) unsigned short lds[65536];
  const int id = blockIdx.x;
  f32x4 acc[8][4];
  if (id < 64) {
    const int p = id >> 2, c = id & 3;       // parent (15,p), K-chunk c
    const size_t koff = (size_t)c * 8 * 64;
    gemm_core<2048>(Qp + (size_t)15 * 256 * 2048 + koff,
                    Kp + (size_t)p * 256 * 2048 + koff, lds, 8, acc);
    ep_f32_at(sc, acc, 3840, p * 256, 4096, scale);
  } else if (id < 184) {
    const int q = id - 64;
    int bm = 0;
    while ((bm + 1) * (bm + 2) / 2 <= q) ++bm;
    const int bn = q - bm * (bm + 1) / 2;
    gemm_core<2048>(Qp + (size_t)bm * 256 * 2048,
                    Kp + (size_t)bn * 256 * 2048, lds, 32, acc);
    ep_f32(sc, acc, bm * 256, bn * 256, 4096, scale);
  } else {
    const int v = id - 184, bm = v >> 4, bn = v & 15;
    gemm_core<2048>(wvb + (size_t)bm * 256 * 2048,
                    xb + (size_t)bn * 256 * 2048, lds, 32, acc);
    ep_bf16(Vt, acc, bm * 256, bn * 256, 4096);
  }
}

// PV half-K split: 256 jobs; half0 -> out, half1 -> aux; out += aux later.
__global__ __launch_bounds__(512, 2)
void pv(const unsigned short* __restrict__ P,
        const unsigned short* __restrict__ Vt, float* __restrict__ out,
        float* __restrict__ aux) {
  __shared__ __align__(16) unsigned short lds[65536];
  const int id = blockIdx.x;
  const int j = id >> 1, h = id & 1;
  const int bm = j >> 3, bn = j & 7;
  const int kt = (bm + 1) * 4;
  const int k0 = h ? (kt >> 1) : 0;
  const int ktl = h ? (kt - (kt >> 1)) : (kt >> 1);
  f32x4 acc[8][4];
  gemm_core<4096>(P + (size_t)bm * 256 * 4096 + (size_t)k0 * 64,
                  Vt + (size_t)bn * 256 * 4096 + (size_t)k0 * 64, lds, ktl, acc);
  if (h) ep_f32(aux, acc, bm * 256, bn * 256, 2048, 1.0f);
  else   ep_f32(out, acc, bm * 256, bn * 256, 2048, 1.0f);
}

__global__ void add_f32(float* __restrict__ out, const float* __restrict__ aux,
                        int n) {
  int i = (blockIdx.x * 256 + threadIdx.x) * 8;
  if (i >= n) return;
  float4 a0 = *(const float4*)(out + i), a1 = *(const float4*)(out + i + 4);
  float4 b0 = *(const float4*)(aux + i), b1 = *(const float4*)(aux + i + 4);
  a0.x += b0.x; a0.y += b0.y; a0.z += b0.z; a0.w += b0.w;
  a1.x += b1.x; a1.y += b1.y; a1.z += b1.z; a1.w += b1.w;
  *(float4*)(out + i) = a0; *(float4*)(out + i + 4) = a1;
}

// ---------------- causal row softmax: scores f32 -> P bf16 ------------------
__global__ void softmax_causal(const float* __restrict__ Sc,
                               unsigned short* __restrict__ P, int S) {
  const int i = blockIdx.x;
  const int tid = threadIdx.x;
  const int nvalid = i + 1;
  const int pad_end = ((i >> 8) + 1) << 8;   // 256-tile boundary
  const float* row = Sc + (size_t)i * S;

  float v[16];
  float m = -1e30f;
#pragma unroll
  for (int it = 0; it < 16; ++it) {
    const int j = tid + it * 256;
    const float x = (j < nvalid) ? row[j] : -1e30f;
    v[it] = x;
    m = fmaxf(m, x);
  }
#pragma unroll
  for (int d = 1; d < 64; d <<= 1) m = fmaxf(m, __shfl_xor(m, d));
  __shared__ float red_m[4], red_s[4];
  const int lane = tid & 63, wv = tid >> 6;
  if (lane == 0) red_m[wv] = m;
  __syncthreads();
  m = fmaxf(fmaxf(red_m[0], red_m[1]), fmaxf(red_m[2], red_m[3]));

  float s = 0.0f;
#pragma unroll
  for (int it = 0; it < 16; ++it) {
    const int j = tid + it * 256;
    const float e = (j < nvalid) ? __expf(v[it] - m) : 0.0f;
    v[it] = e;
    s += e;
  }
#pragma unroll
  for (int d = 1; d < 64; d <<= 1) s += __shfl_xor(s, d);
  if (lane == 0) red_s[wv] = s;
  __syncthreads();
  s = red_s[0] + red_s[1] + red_s[2] + red_s[3];

  const float inv = 1.0f / s;
  unsigned short* prow = P + (size_t)i * S;
#pragma unroll
  for (int it = 0; it < 16; ++it) {
    const int j = tid + it * 256;
    if (j < pad_end) prow[j] = (j < nvalid) ? f2bf(v[it] * inv) : (unsigned short)0;
  }
}

// ---------------- launch -----------------------------------------------------
extern "C" void kernel_launch(void* const* d_in, const int* in_sizes, int n_in,
                              void* d_out, int out_size, void* d_ws, size_t ws_size,
                              hipStream_t stream) {
  const float* x  = (const float*)d_in[0];
  const float* Wq = (const float*)d_in[1];
  const float* Wk = (const float*)d_in[2];
  const float* Wv = (const float*)d_in[3];
  float* out = (float*)d_out;

  const int S = 4096, D = 2048;
  char* ws = (char*)d_ws;
  const size_t MB = 1u << 20;
  // Workspace (peak 136 MiB):
  //   sc  [  0, 64)  f32 scores            live: vt_qkt .. softmax
  //   aux [  0, 32)  pv half1 (over sc)    live: pv .. add
  //   xb  [ 64, 80)                        live: cvt .. vt_qkt
  //   wqb [ 80, 88)  wkb [88,96)           live: cvt .. proj_qk
  //   wvb [ 96,104)                        live: cvt .. vt_qkt
  //   Q   [104,120)  Kb [120,136)          live: proj_qk .. vt_qkt
  //   Vt  [ 80, 96)  (over wqb/wkb)        live: vt_qkt .. pv
  //   P   [104,136)  (over Q/Kb)           live: softmax .. pv
  float*          sc  = (float*)ws;
  float*          aux = (float*)ws;
  unsigned short* xb  = (unsigned short*)(ws + 64 * MB);
  unsigned short* wqb = (unsigned short*)(ws + 80 * MB);
  unsigned short* wkb = (unsigned short*)(ws + 88 * MB);
  unsigned short* wvb = (unsigned short*)(ws + 96 * MB);
  unsigned short* Q   = (unsigned short*)(ws + 104 * MB);
  unsigned short* Kb  = (unsigned short*)(ws + 120 * MB);
  unsigned short* Vt  = (unsigned short*)(ws + 80 * MB);
  unsigned short* P   = (unsigned short*)(ws + 104 * MB);

  cvt_f32_bf16<<<(S * D) / (256 * 8), 256, 0, stream>>>(x, xb, S * D);
  cvt_f32_bf16<<<(D * D) / (256 * 8), 256, 0, stream>>>(Wq, wqb, D * D);
  cvt_f32_bf16<<<(D * D) / (256 * 8), 256, 0, stream>>>(Wk, wkb, D * D);
  cvt_f32_bf16<<<(D * D) / (256 * 8), 256, 0, stream>>>(Wv, wvb, D * D);

  proj_qk<<<256, 512, 0, stream>>>(xb, wqb, wkb, Q, Kb);

  // zero sc rows 3840..4095 (atomicAdd targets of the K-chunk jobs)
  hipMemsetAsync(sc + (size_t)3840 * 4096, 0, (size_t)256 * 4096 * 4, stream);

  const float scale = 1.0f / sqrtf((float)D);
  vt_qkt<<<312, 512, 0, stream>>>(Q, Kb, wvb, xb, sc, Vt, scale);

  softmax_causal<<<S, 256, 0, stream>>>(sc, P, S);

  pv<<<256, 512, 0, stream>>>(P, Vt, out, aux);
  add_f32<<<(S * D) / (256 * 8), 256, 0, stream>>>(out, aux, S * D);
}